// Round 1
// baseline (3677.383 us; speedup 1.0000x reference)
//
#include <hip/hip_runtime.h>
#include <hip/hip_bf16.h>

#define NN 50000
#define NE 800000

__global__ void count_deg_k(const int* __restrict__ ei, float* __restrict__ deg) {
    int e = blockIdx.x * blockDim.x + threadIdx.x;
    if (e < NE) atomicAdd(&deg[ei[NE + e]], 1.0f);
}

__global__ void inv_k(float* __restrict__ deg) {
    int i = blockIdx.x * blockDim.x + threadIdx.x;
    if (i < NN) deg[i] = 1.0f / fmaxf(deg[i], 1.0f);
}

template<int M>
__global__ void scatter_k(const int* __restrict__ ei, const float* __restrict__ Y,
                          float* __restrict__ agg) {
    constexpr int CH = M / 4;
    long long t = (long long)blockIdx.x * blockDim.x + threadIdx.x;
    int e = (int)(t / CH);
    if (e >= NE) return;
    int c = ((int)(t % CH)) * 4;
    int s = ei[e];
    int d = ei[NE + e];
    const float4 v = *reinterpret_cast<const float4*>(&Y[(size_t)s * M + c]);
    float* p = &agg[(size_t)d * M + c];
    atomicAdd(p + 0, v.x);
    atomicAdd(p + 1, v.y);
    atomicAdd(p + 2, v.z);
    atomicAdd(p + 3, v.w);
}

// MODE 0: out = A@W
// MODE 1: out = ELU(agg*inv + A@W + bias)
// MODE 2: out =     agg*inv + A@W + bias   (no activation, last layer logits)
template<int M, int MODE>
__global__ __launch_bounds__(256) void gemm_k(
    const float* __restrict__ A, const float* __restrict__ W,
    const float* __restrict__ bias, const float* __restrict__ agg,
    const float* __restrict__ inv, float* __restrict__ out)
{
    constexpr int K = 128;
    constexpr int TC = M / 4;        // thread-cols
    constexpr int TRW = 256 / TC;    // thread-rows
    constexpr int TILE_R = TRW * 4;  // rows per block: 32 (M=128) or 64 (M=64)
    __shared__ float Ws[K][M];
    __shared__ float As[TILE_R][K];
    const int row0 = blockIdx.x * TILE_R;

    for (int i = threadIdx.x; i < K * M / 4; i += 256)
        reinterpret_cast<float4*>(&Ws[0][0])[i] = reinterpret_cast<const float4*>(W)[i];
    for (int i = threadIdx.x; i < TILE_R * (K / 4); i += 256) {
        int r = i / (K / 4), c4 = (i % (K / 4)) * 4;
        int row = row0 + r;
        float4 v = make_float4(0.f, 0.f, 0.f, 0.f);
        if (row < NN) v = *reinterpret_cast<const float4*>(&A[(size_t)row * K + c4]);
        *reinterpret_cast<float4*>(&As[r][c4]) = v;
    }
    __syncthreads();

    const int tc = (threadIdx.x % TC) * 4;
    const int tr = (threadIdx.x / TC) * 4;
    float acc[4][4] = {};
    #pragma unroll 4
    for (int k = 0; k < K; k += 4) {
        float4 a[4], b[4];
        #pragma unroll
        for (int i = 0; i < 4; ++i) a[i] = *reinterpret_cast<const float4*>(&As[tr + i][k]);
        #pragma unroll
        for (int j = 0; j < 4; ++j) b[j] = *reinterpret_cast<const float4*>(&Ws[k + j][tc]);
        #pragma unroll
        for (int i = 0; i < 4; ++i) {
            const float ax = a[i].x, ay = a[i].y, az = a[i].z, aw = a[i].w;
            acc[i][0] += ax * b[0].x + ay * b[1].x + az * b[2].x + aw * b[3].x;
            acc[i][1] += ax * b[0].y + ay * b[1].y + az * b[2].y + aw * b[3].y;
            acc[i][2] += ax * b[0].z + ay * b[1].z + az * b[2].z + aw * b[3].z;
            acc[i][3] += ax * b[0].w + ay * b[1].w + az * b[2].w + aw * b[3].w;
        }
    }

    #pragma unroll
    for (int i = 0; i < 4; ++i) {
        int row = row0 + tr + i;
        if (row >= NN) break;
        float4 r;
        r.x = acc[i][0]; r.y = acc[i][1]; r.z = acc[i][2]; r.w = acc[i][3];
        if (MODE >= 1) {
            const float iv = inv[row];
            const float4 g = *reinterpret_cast<const float4*>(&agg[(size_t)row * M + tc]);
            r.x += g.x * iv + bias[tc + 0];
            r.y += g.y * iv + bias[tc + 1];
            r.z += g.z * iv + bias[tc + 2];
            r.w += g.w * iv + bias[tc + 3];
            if (MODE == 1) {
                r.x = r.x > 0.f ? r.x : expf(r.x) - 1.f;
                r.y = r.y > 0.f ? r.y : expf(r.y) - 1.f;
                r.z = r.z > 0.f ? r.z : expf(r.z) - 1.f;
                r.w = r.w > 0.f ? r.w : expf(r.w) - 1.f;
            }
        }
        *reinterpret_cast<float4*>(&out[(size_t)row * M + tc]) = r;
    }
}

__global__ void lsm_k(float* __restrict__ h) {  // in-place log_softmax on [NN][64]
    int wid = (int)((blockIdx.x * (long long)blockDim.x + threadIdx.x) >> 6);
    int lane = threadIdx.x & 63;
    if (wid >= NN) return;
    float v = h[(size_t)wid * 64 + lane];
    float m = v;
    #pragma unroll
    for (int o = 32; o >= 1; o >>= 1) m = fmaxf(m, __shfl_xor(m, o, 64));
    float ex = expf(v - m);
    float s = ex;
    #pragma unroll
    for (int o = 32; o >= 1; o >>= 1) s += __shfl_xor(s, o, 64);
    h[(size_t)wid * 64 + lane] = v - m - logf(s);
}

extern "C" void kernel_launch(void* const* d_in, const int* in_sizes, int n_in,
                              void* d_out, int out_size, void* d_ws, size_t ws_size,
                              hipStream_t stream) {
    const float* x   = (const float*)d_in[0];
    const int*   ei  = (const int*)d_in[1];
    const float* Wl0 = (const float*)d_in[2];
    const float* bl0 = (const float*)d_in[3];
    const float* Wr0 = (const float*)d_in[4];
    const float* Wl1 = (const float*)d_in[5];
    const float* bl1 = (const float*)d_in[6];
    const float* Wr1 = (const float*)d_in[7];
    const float* Wl2 = (const float*)d_in[8];
    const float* bl2 = (const float*)d_in[9];
    const float* Wr2 = (const float*)d_in[10];
    float* out = (float*)d_out;

    char* ws = (char*)d_ws;
    float* Y   = (float*)(ws);
    float* agg = (float*)(ws + (size_t)NN * 128 * 4);
    float* H   = (float*)(ws + (size_t)NN * 128 * 4 * 2);
    float* deg = (float*)(ws + (size_t)NN * 128 * 4 * 3);

    hipMemsetAsync(deg, 0, NN * sizeof(float), stream);
    count_deg_k<<<(NE + 255) / 256, 256, 0, stream>>>(ei, deg);
    inv_k<<<(NN + 255) / 256, 256, 0, stream>>>(deg);  // deg[] now holds 1/max(deg,1)

    const int GB128 = (NN + 31) / 32;
    const int GB64  = (NN + 63) / 64;

    // Layer 1: input x
    gemm_k<128, 0><<<GB128, 256, 0, stream>>>(x, Wl0, nullptr, nullptr, nullptr, Y);
    hipMemsetAsync(agg, 0, (size_t)NN * 128 * 4, stream);
    scatter_k<128><<<(NE * 32 + 255) / 256, 256, 0, stream>>>(ei, Y, agg);
    gemm_k<128, 1><<<GB128, 256, 0, stream>>>(x, Wr0, bl0, agg, deg, H);

    // Layer 2: input H (in-place update is block-row-local safe)
    gemm_k<128, 0><<<GB128, 256, 0, stream>>>(H, Wl1, nullptr, nullptr, nullptr, Y);
    hipMemsetAsync(agg, 0, (size_t)NN * 128 * 4, stream);
    scatter_k<128><<<(NE * 32 + 255) / 256, 256, 0, stream>>>(ei, Y, agg);
    gemm_k<128, 1><<<GB128, 256, 0, stream>>>(H, Wr1, bl1, agg, deg, H);

    // Layer 3: input H, logits -> d_out
    gemm_k<64, 0><<<GB64, 256, 0, stream>>>(H, Wl2, nullptr, nullptr, nullptr, Y);
    hipMemsetAsync(agg, 0, (size_t)NN * 64 * 4, stream);
    scatter_k<64><<<(NE * 16 + 255) / 256, 256, 0, stream>>>(ei, Y, agg);
    gemm_k<64, 2><<<GB64, 256, 0, stream>>>(H, Wr2, bl2, agg, deg, out);

    lsm_k<<<(NN + 3) / 4, 256, 0, stream>>>(out);
}

// Round 2
// 481.660 us; speedup vs baseline: 7.6348x; 7.6348x over previous
//
#include <hip/hip_runtime.h>
#include <hip/hip_bf16.h>

#define NN 50000
#define NE 800000

// ---------------- CSR build ----------------

__global__ void count_deg_k(const int* __restrict__ ei, int* __restrict__ cnt) {
    int e = blockIdx.x * blockDim.x + threadIdx.x;
    if (e < NE) atomicAdd(&cnt[ei[NE + e]], 1);
}

// per-block exclusive scan (256 elems/block) + block sums
__global__ void scan_block_k(const int* __restrict__ cnt, int* __restrict__ rowptr,
                             int* __restrict__ bsum) {
    __shared__ int s[256];
    int tid = threadIdx.x;
    int i = blockIdx.x * 256 + tid;
    int v = (i < NN) ? cnt[i] : 0;
    s[tid] = v;
    __syncthreads();
    #pragma unroll
    for (int off = 1; off < 256; off <<= 1) {
        int t = (tid >= off) ? s[tid - off] : 0;
        __syncthreads();
        s[tid] += t;
        __syncthreads();
    }
    if (i < NN) rowptr[i] = s[tid] - v;  // exclusive
    if (tid == 255) bsum[blockIdx.x] = s[255];
}

// single-block exclusive scan of <=256 block sums
__global__ void scan_bsum_k(int* __restrict__ bsum, int nb) {
    __shared__ int s[256];
    int tid = threadIdx.x;
    int v = (tid < nb) ? bsum[tid] : 0;
    s[tid] = v;
    __syncthreads();
    #pragma unroll
    for (int off = 1; off < 256; off <<= 1) {
        int t = (tid >= off) ? s[tid - off] : 0;
        __syncthreads();
        s[tid] += t;
        __syncthreads();
    }
    if (tid < nb) bsum[tid] = s[tid] - v;
}

__global__ void scan_add_k(int* __restrict__ rowptr, const int* __restrict__ bsum) {
    int i = blockIdx.x * 256 + threadIdx.x;
    if (i < NN) rowptr[i] += bsum[blockIdx.x];
    if (i == 0) rowptr[NN] = NE;
}

__global__ void fill_k(const int* __restrict__ ei, const int* __restrict__ rowptr,
                       int* __restrict__ cursor, int* __restrict__ csr_src) {
    int e = blockIdx.x * blockDim.x + threadIdx.x;
    if (e >= NE) return;
    int d = ei[NE + e];
    int p = rowptr[d] + atomicAdd(&cursor[d], 1);
    csr_src[p] = ei[e];
}

// ---------------- per-layer kernels ----------------

// agg[n] = mean over neighbors src of Y[src]  (isolated nodes -> 0)
template<int M>
__global__ __launch_bounds__(256) void gather_k(const int* __restrict__ rowptr,
                                                const int* __restrict__ csr_src,
                                                const float* __restrict__ Y,
                                                float* __restrict__ agg) {
    constexpr int GSZ = M / 4;        // lanes per node
    constexpr int GPB = 256 / GSZ;    // nodes per block
    const int g = threadIdx.x / GSZ;
    const int l = (threadIdx.x % GSZ) * 4;
    const int n = blockIdx.x * GPB + g;
    if (n >= NN) return;
    const int beg = rowptr[n], end = rowptr[n + 1];
    const float inv = 1.0f / fmaxf((float)(end - beg), 1.0f);
    float ax = 0.f, ay = 0.f, az = 0.f, aw = 0.f;
    int e = beg;
    for (; e + 1 < end; e += 2) {
        const int s0 = csr_src[e], s1 = csr_src[e + 1];
        const float4 v0 = *reinterpret_cast<const float4*>(&Y[(size_t)s0 * M + l]);
        const float4 v1 = *reinterpret_cast<const float4*>(&Y[(size_t)s1 * M + l]);
        ax += v0.x + v1.x; ay += v0.y + v1.y; az += v0.z + v1.z; aw += v0.w + v1.w;
    }
    if (e < end) {
        const int s0 = csr_src[e];
        const float4 v0 = *reinterpret_cast<const float4*>(&Y[(size_t)s0 * M + l]);
        ax += v0.x; ay += v0.y; az += v0.z; aw += v0.w;
    }
    float4 r;
    r.x = ax * inv; r.y = ay * inv; r.z = az * inv; r.w = aw * inv;
    *reinterpret_cast<float4*>(&agg[(size_t)n * M + l]) = r;
}

// MODE 0: out = A@W
// MODE 1: out = ELU(agg + A@W + bias)
// MODE 2: out =     agg + A@W + bias
template<int M, int MODE>
__global__ __launch_bounds__(256) void gemm_k(
    const float* __restrict__ A, const float* __restrict__ W,
    const float* __restrict__ bias, const float* __restrict__ agg,
    float* __restrict__ out)
{
    constexpr int K = 128;
    constexpr int TC = M / 4;
    constexpr int TRW = 256 / TC;
    constexpr int TILE_R = TRW * 4;
    __shared__ float Ws[K][M];
    __shared__ float As[TILE_R][K];
    const int row0 = blockIdx.x * TILE_R;

    for (int i = threadIdx.x; i < K * M / 4; i += 256)
        reinterpret_cast<float4*>(&Ws[0][0])[i] = reinterpret_cast<const float4*>(W)[i];
    for (int i = threadIdx.x; i < TILE_R * (K / 4); i += 256) {
        int r = i / (K / 4), c4 = (i % (K / 4)) * 4;
        int row = row0 + r;
        float4 v = make_float4(0.f, 0.f, 0.f, 0.f);
        if (row < NN) v = *reinterpret_cast<const float4*>(&A[(size_t)row * K + c4]);
        *reinterpret_cast<float4*>(&As[r][c4]) = v;
    }
    __syncthreads();

    const int tc = (threadIdx.x % TC) * 4;
    const int tr = (threadIdx.x / TC) * 4;
    float acc[4][4] = {};
    #pragma unroll 4
    for (int k = 0; k < K; k += 4) {
        float4 a[4], b[4];
        #pragma unroll
        for (int i = 0; i < 4; ++i) a[i] = *reinterpret_cast<const float4*>(&As[tr + i][k]);
        #pragma unroll
        for (int j = 0; j < 4; ++j) b[j] = *reinterpret_cast<const float4*>(&Ws[k + j][tc]);
        #pragma unroll
        for (int i = 0; i < 4; ++i) {
            const float ax = a[i].x, ay = a[i].y, az = a[i].z, aw = a[i].w;
            acc[i][0] += ax * b[0].x + ay * b[1].x + az * b[2].x + aw * b[3].x;
            acc[i][1] += ax * b[0].y + ay * b[1].y + az * b[2].y + aw * b[3].y;
            acc[i][2] += ax * b[0].z + ay * b[1].z + az * b[2].z + aw * b[3].z;
            acc[i][3] += ax * b[0].w + ay * b[1].w + az * b[2].w + aw * b[3].w;
        }
    }

    #pragma unroll
    for (int i = 0; i < 4; ++i) {
        int row = row0 + tr + i;
        if (row >= NN) break;
        float4 r;
        r.x = acc[i][0]; r.y = acc[i][1]; r.z = acc[i][2]; r.w = acc[i][3];
        if (MODE >= 1) {
            const float4 g = *reinterpret_cast<const float4*>(&agg[(size_t)row * M + tc]);
            r.x += g.x + bias[tc + 0];
            r.y += g.y + bias[tc + 1];
            r.z += g.z + bias[tc + 2];
            r.w += g.w + bias[tc + 3];
            if (MODE == 1) {
                r.x = r.x > 0.f ? r.x : expf(r.x) - 1.f;
                r.y = r.y > 0.f ? r.y : expf(r.y) - 1.f;
                r.z = r.z > 0.f ? r.z : expf(r.z) - 1.f;
                r.w = r.w > 0.f ? r.w : expf(r.w) - 1.f;
            }
        }
        *reinterpret_cast<float4*>(&out[(size_t)row * M + tc]) = r;
    }
}

__global__ void lsm_k(float* __restrict__ h) {  // in-place log_softmax on [NN][64]
    int wid = (int)((blockIdx.x * (long long)blockDim.x + threadIdx.x) >> 6);
    int lane = threadIdx.x & 63;
    if (wid >= NN) return;
    float v = h[(size_t)wid * 64 + lane];
    float m = v;
    #pragma unroll
    for (int o = 32; o >= 1; o >>= 1) m = fmaxf(m, __shfl_xor(m, o, 64));
    float ex = expf(v - m);
    float s = ex;
    #pragma unroll
    for (int o = 32; o >= 1; o >>= 1) s += __shfl_xor(s, o, 64);
    h[(size_t)wid * 64 + lane] = v - m - logf(s);
}

extern "C" void kernel_launch(void* const* d_in, const int* in_sizes, int n_in,
                              void* d_out, int out_size, void* d_ws, size_t ws_size,
                              hipStream_t stream) {
    const float* x   = (const float*)d_in[0];
    const int*   ei  = (const int*)d_in[1];
    const float* Wl0 = (const float*)d_in[2];
    const float* bl0 = (const float*)d_in[3];
    const float* Wr0 = (const float*)d_in[4];
    const float* Wl1 = (const float*)d_in[5];
    const float* bl1 = (const float*)d_in[6];
    const float* Wr1 = (const float*)d_in[7];
    const float* Wl2 = (const float*)d_in[8];
    const float* bl2 = (const float*)d_in[9];
    const float* Wr2 = (const float*)d_in[10];
    float* out = (float*)d_out;

    float* Y      = (float*)d_ws;
    float* agg    = Y + (size_t)NN * 128;
    float* H      = agg + (size_t)NN * 128;
    int*   rowptr = (int*)(H + (size_t)NN * 128);   // NN+1
    int*   cursor = rowptr + (NN + 2);              // NN
    int*   bsum   = cursor + NN;                    // 256
    int*   csr    = bsum + 256;                     // NE

    const int NB = (NN + 255) / 256;  // 196 <= 256

    // ---- CSR build (once; shared by all 3 layers) ----
    hipMemsetAsync(cursor, 0, NN * sizeof(int), stream);
    count_deg_k<<<(NE + 255) / 256, 256, 0, stream>>>(ei, cursor);
    scan_block_k<<<NB, 256, 0, stream>>>(cursor, rowptr, bsum);
    scan_bsum_k<<<1, 256, 0, stream>>>(bsum, NB);
    scan_add_k<<<NB, 256, 0, stream>>>(rowptr, bsum);
    hipMemsetAsync(cursor, 0, NN * sizeof(int), stream);
    fill_k<<<(NE + 255) / 256, 256, 0, stream>>>(ei, rowptr, cursor, csr);

    const int GB128 = (NN + 31) / 32;
    const int GB64  = (NN + 63) / 64;
    const int AG128 = (NN + 7) / 8;    // gather_k<128>: 8 nodes/block
    const int AG64  = (NN + 15) / 16;  // gather_k<64>: 16 nodes/block

    // Layer 1: input x
    gemm_k<128, 0><<<GB128, 256, 0, stream>>>(x, Wl0, nullptr, nullptr, Y);
    gather_k<128><<<AG128, 256, 0, stream>>>(rowptr, csr, Y, agg);
    gemm_k<128, 1><<<GB128, 256, 0, stream>>>(x, Wr0, bl0, agg, H);

    // Layer 2: input H (in-place safe: block stages its rows before writing)
    gemm_k<128, 0><<<GB128, 256, 0, stream>>>(H, Wl1, nullptr, nullptr, Y);
    gather_k<128><<<AG128, 256, 0, stream>>>(rowptr, csr, Y, agg);
    gemm_k<128, 1><<<GB128, 256, 0, stream>>>(H, Wr1, bl1, agg, H);

    // Layer 3: input H -> logits in d_out
    gemm_k<64, 0><<<GB64, 256, 0, stream>>>(H, Wl2, nullptr, nullptr, Y);
    gather_k<64><<<AG64, 256, 0, stream>>>(rowptr, csr, Y, agg);
    gemm_k<64, 2><<<GB64, 256, 0, stream>>>(H, Wr2, bl2, agg, out);

    lsm_k<<<(NN + 3) / 4, 256, 0, stream>>>(out);
}

// Round 3
// 240.960 us; speedup vs baseline: 15.2614x; 1.9989x over previous
//
#include <hip/hip_runtime.h>
#include <hip/hip_bf16.h>

#define NN 50000
#define NE 800000
#define NPAD 50048  // rows padded to multiple of 64

typedef __attribute__((ext_vector_type(8))) short bf8;   // 8 bf16 = 4 VGPR
typedef __attribute__((ext_vector_type(4))) float f4;

__device__ __forceinline__ unsigned short f2bf(float f) {  // RNE
    union { float f; unsigned int u; } x; x.f = f;
    unsigned int r = x.u + 0x7fffu + ((x.u >> 16) & 1u);
    return (unsigned short)(r >> 16);
}
__device__ __forceinline__ float b2f(short s) {
    union { unsigned int u; float f; } x;
    x.u = ((unsigned int)(unsigned short)s) << 16;
    return x.f;
}

// ---------------- CSR build ----------------

__global__ void count_deg_k(const int* __restrict__ ei, int* __restrict__ cnt) {
    int e = blockIdx.x * blockDim.x + threadIdx.x;
    if (e < NE) atomicAdd(&cnt[ei[NE + e]], 1);
}

__global__ void scan_block_k(const int* __restrict__ cnt, int* __restrict__ rowptr,
                             int* __restrict__ bsum) {
    __shared__ int s[256];
    int tid = threadIdx.x;
    int i = blockIdx.x * 256 + tid;
    int v = (i < NN) ? cnt[i] : 0;
    s[tid] = v;
    __syncthreads();
    #pragma unroll
    for (int off = 1; off < 256; off <<= 1) {
        int t = (tid >= off) ? s[tid - off] : 0;
        __syncthreads();
        s[tid] += t;
        __syncthreads();
    }
    if (i < NN) rowptr[i] = s[tid] - v;
    if (tid == 255) bsum[blockIdx.x] = s[255];
}

__global__ void scan_bsum_k(int* __restrict__ bsum, int nb) {
    __shared__ int s[256];
    int tid = threadIdx.x;
    int v = (tid < nb) ? bsum[tid] : 0;
    s[tid] = v;
    __syncthreads();
    #pragma unroll
    for (int off = 1; off < 256; off <<= 1) {
        int t = (tid >= off) ? s[tid - off] : 0;
        __syncthreads();
        s[tid] += t;
        __syncthreads();
    }
    if (tid < nb) bsum[tid] = s[tid] - v;
}

__global__ void scan_add_k(int* __restrict__ rowptr, const int* __restrict__ bsum) {
    int i = blockIdx.x * 256 + threadIdx.x;
    if (i < NN) rowptr[i] += bsum[blockIdx.x];
    if (i == 0) rowptr[NN] = NE;
}

__global__ void fill_k(const int* __restrict__ ei, const int* __restrict__ rowptr,
                       int* __restrict__ cursor, int* __restrict__ csr_src) {
    int e = blockIdx.x * blockDim.x + threadIdx.x;
    if (e >= NE) return;
    int d = ei[NE + e];
    int p = rowptr[d] + atomicAdd(&cursor[d], 1);
    csr_src[p] = ei[e];
}

// ---------------- prep: fp32 -> bf16 ----------------

__global__ void cvt_x_k(const float* __restrict__ x, unsigned short* __restrict__ x16) {
    int i = blockIdx.x * 256 + threadIdx.x;             // one thread = 8 elems
    if (i >= NPAD * 128 / 8) return;
    bf8 o;
    if (i < NN * 128 / 8) {
        const float4 a = reinterpret_cast<const float4*>(x)[i * 2];
        const float4 b = reinterpret_cast<const float4*>(x)[i * 2 + 1];
        o[0] = (short)f2bf(a.x); o[1] = (short)f2bf(a.y);
        o[2] = (short)f2bf(a.z); o[3] = (short)f2bf(a.w);
        o[4] = (short)f2bf(b.x); o[5] = (short)f2bf(b.y);
        o[6] = (short)f2bf(b.z); o[7] = (short)f2bf(b.w);
    } else {
        o = (bf8){0,0,0,0,0,0,0,0};
    }
    *reinterpret_cast<bf8*>(&x16[i * 8]) = o;
}

// pack B = [Wl | Wr] (fp32, row-major [128][Mo] each) into bf16 MFMA B-fragment layout:
// Bp[((cf*4+ks)*64 + lane)*8 + i] = B[ks*32 + (lane>>4)*8 + i][cf*16 + (lane&15)]
__global__ void pack_w_k(const float* __restrict__ Wl, const float* __restrict__ Wr,
                         int Mo, unsigned short* __restrict__ Bp) {
    int idx = blockIdx.x * 256 + threadIdx.x;
    int ncol = 2 * Mo;
    if (idx >= 128 * ncol) return;
    int k = idx / ncol, c = idx % ncol;
    float v = (c < Mo) ? Wl[k * Mo + c] : Wr[k * Mo + (c - Mo)];
    int cf = c >> 4, ks = k >> 5;
    int lane = (c & 15) | (((k & 31) >> 3) << 4);
    int i = k & 7;
    Bp[(((cf << 2) | ks) * 64 + lane) * 8 + i] = f2bf(v);
}

// ---------------- fused dual GEMM:  C[r][0:NCOL] = A[r][0:128] @ [Wl|Wr] ----------------
// block = 4 waves, 64 rows; wave w owns cols [w*CFW*16, (w+1)*CFW*16)
template<int NCOL>
__global__ __launch_bounds__(256) void gemm16_k(const unsigned short* __restrict__ A,
                                                const unsigned short* __restrict__ Bp,
                                                unsigned short* __restrict__ C) {
    constexpr int CFW = NCOL / 64;           // colfrags per wave (4 or 2)
    const int wave = threadIdx.x >> 6;
    const int lane = threadIdx.x & 63;
    const int r0 = blockIdx.x * 64;

    bf8 bfr[CFW][4];
    const bf8* bp = reinterpret_cast<const bf8*>(Bp);
    #pragma unroll
    for (int cf = 0; cf < CFW; ++cf)
        #pragma unroll
        for (int ks = 0; ks < 4; ++ks)
            bfr[cf][ks] = bp[((wave * CFW + cf) * 4 + ks) * 64 + lane];

    const int rlane = lane & 15, kc = lane >> 4;
    #pragma unroll
    for (int rf = 0; rf < 4; ++rf) {
        const int arow = r0 + rf * 16 + rlane;
        const bf8* ap = reinterpret_cast<const bf8*>(A + (size_t)arow * 128);
        bf8 afr[4];
        #pragma unroll
        for (int ks = 0; ks < 4; ++ks) afr[ks] = ap[ks * 4 + kc];
        f4 acc[CFW];
        #pragma unroll
        for (int cf = 0; cf < CFW; ++cf) acc[cf] = (f4){0.f, 0.f, 0.f, 0.f};
        #pragma unroll
        for (int ks = 0; ks < 4; ++ks)
            #pragma unroll
            for (int cf = 0; cf < CFW; ++cf)
                acc[cf] = __builtin_amdgcn_mfma_f32_16x16x32_bf16(afr[ks], bfr[cf][ks], acc[cf], 0, 0, 0);
        // D layout: col = lane&15, row = (lane>>4)*4 + j
        const int orow0 = r0 + rf * 16 + (lane >> 4) * 4;
        #pragma unroll
        for (int j = 0; j < 4; ++j) {
            const int orow = orow0 + j;
            if (orow < NN) {
                #pragma unroll
                for (int cf = 0; cf < CFW; ++cf)
                    C[(size_t)orow * NCOL + (wave * CFW + cf) * 16 + rlane] = f2bf(acc[cf][j]);
            }
        }
    }
}

// ---------------- gather + combine (+ELU or +log_softmax) ----------------
// C rows are [Y(MO cols) | Z(MO cols)].  h = agg_mean(Y[neigh]) + Z + bias
template<int MO, bool LAST>
__global__ __launch_bounds__(256) void gathcomb_k(const int* __restrict__ rowptr,
                                                  const int* __restrict__ csr,
                                                  const unsigned short* __restrict__ C,
                                                  const float* __restrict__ bias,
                                                  unsigned short* __restrict__ Hout,
                                                  float* __restrict__ lout) {
    constexpr int NCOL = 2 * MO;
    constexpr int GSZ = MO / 8;          // lanes per node
    constexpr int NPB = 256 / GSZ;       // nodes per block
    const int g = threadIdx.x / GSZ;
    const int l = threadIdx.x % GSZ;
    const int n = blockIdx.x * NPB + g;
    if (n >= NN) return;
    const int beg = rowptr[n], end = rowptr[n + 1];

    float acc[8] = {0.f, 0.f, 0.f, 0.f, 0.f, 0.f, 0.f, 0.f};
    int e = beg;
    for (; e + 1 < end; e += 2) {
        const int s0 = csr[e], s1 = csr[e + 1];
        const bf8 v0 = *reinterpret_cast<const bf8*>(&C[(size_t)s0 * NCOL + l * 8]);
        const bf8 v1 = *reinterpret_cast<const bf8*>(&C[(size_t)s1 * NCOL + l * 8]);
        #pragma unroll
        for (int i = 0; i < 8; ++i) acc[i] += b2f(v0[i]) + b2f(v1[i]);
    }
    if (e < end) {
        const int s0 = csr[e];
        const bf8 v0 = *reinterpret_cast<const bf8*>(&C[(size_t)s0 * NCOL + l * 8]);
        #pragma unroll
        for (int i = 0; i < 8; ++i) acc[i] += b2f(v0[i]);
    }
    const float inv = 1.0f / fmaxf((float)(end - beg), 1.0f);
    const bf8 z = *reinterpret_cast<const bf8*>(&C[(size_t)n * NCOL + MO + l * 8]);
    float h[8];
    #pragma unroll
    for (int i = 0; i < 8; ++i) h[i] = acc[i] * inv + b2f(z[i]) + bias[l * 8 + i];

    if (!LAST) {
        bf8 o;
        #pragma unroll
        for (int i = 0; i < 8; ++i) {
            const float v = h[i] > 0.f ? h[i] : expf(h[i]) - 1.f;  // ELU
            o[i] = (short)f2bf(v);
        }
        *reinterpret_cast<bf8*>(&Hout[(size_t)n * MO + l * 8]) = o;
    } else {
        float m = h[0];
        #pragma unroll
        for (int i = 1; i < 8; ++i) m = fmaxf(m, h[i]);
        #pragma unroll
        for (int o = 1; o < GSZ; o <<= 1) m = fmaxf(m, __shfl_xor(m, o, 64));
        float s = 0.f;
        #pragma unroll
        for (int i = 0; i < 8; ++i) s += expf(h[i] - m);
        #pragma unroll
        for (int o = 1; o < GSZ; o <<= 1) s += __shfl_xor(s, o, 64);
        const float lg = m + logf(s);
        float4 o0, o1;
        o0.x = h[0] - lg; o0.y = h[1] - lg; o0.z = h[2] - lg; o0.w = h[3] - lg;
        o1.x = h[4] - lg; o1.y = h[5] - lg; o1.z = h[6] - lg; o1.w = h[7] - lg;
        float* op = &lout[(size_t)n * MO + l * 8];
        *reinterpret_cast<float4*>(op) = o0;
        *reinterpret_cast<float4*>(op + 4) = o1;
    }
}

extern "C" void kernel_launch(void* const* d_in, const int* in_sizes, int n_in,
                              void* d_out, int out_size, void* d_ws, size_t ws_size,
                              hipStream_t stream) {
    const float* x   = (const float*)d_in[0];
    const int*   ei  = (const int*)d_in[1];
    const float* Wl0 = (const float*)d_in[2];
    const float* bl0 = (const float*)d_in[3];
    const float* Wr0 = (const float*)d_in[4];
    const float* Wl1 = (const float*)d_in[5];
    const float* bl1 = (const float*)d_in[6];
    const float* Wr1 = (const float*)d_in[7];
    const float* Wl2 = (const float*)d_in[8];
    const float* bl2 = (const float*)d_in[9];
    const float* Wr2 = (const float*)d_in[10];
    float* out = (float*)d_out;

    unsigned short* x16  = (unsigned short*)d_ws;              // [NPAD][128]
    unsigned short* H    = x16 + (size_t)NPAD * 128;           // [NPAD][128]
    unsigned short* Cbuf = H + (size_t)NPAD * 128;             // [NPAD][256]
    unsigned short* Bp0  = Cbuf + (size_t)NPAD * 256;          // 128*256
    unsigned short* Bp1  = Bp0 + 128 * 256;
    unsigned short* Bp2  = Bp1 + 128 * 256;                    // 128*128
    int* rowptr = (int*)(Bp2 + 128 * 128);                     // NN+2
    int* cursor = rowptr + (NN + 2);
    int* bsum   = cursor + NN;                                 // 256
    int* csr    = bsum + 256;                                  // NE

    const int NB = (NN + 255) / 256;

    // ---- CSR build ----
    hipMemsetAsync(cursor, 0, NN * sizeof(int), stream);
    count_deg_k<<<(NE + 255) / 256, 256, 0, stream>>>(ei, cursor);
    scan_block_k<<<NB, 256, 0, stream>>>(cursor, rowptr, bsum);
    scan_bsum_k<<<1, 256, 0, stream>>>(bsum, NB);
    scan_add_k<<<NB, 256, 0, stream>>>(rowptr, bsum);
    hipMemsetAsync(cursor, 0, NN * sizeof(int), stream);
    fill_k<<<(NE + 255) / 256, 256, 0, stream>>>(ei, rowptr, cursor, csr);

    // ---- prep bf16 ----
    cvt_x_k<<<(NPAD * 128 / 8 + 255) / 256, 256, 0, stream>>>(x, x16);
    pack_w_k<<<(128 * 256 + 255) / 256, 256, 0, stream>>>(Wl0, Wr0, 128, Bp0);
    pack_w_k<<<(128 * 256 + 255) / 256, 256, 0, stream>>>(Wl1, Wr1, 128, Bp1);
    pack_w_k<<<(128 * 128 + 255) / 256, 256, 0, stream>>>(Wl2, Wr2, 64, Bp2);

    const int GB = NPAD / 64;               // 782
    const int AG128 = (NN + 15) / 16;       // gathcomb<128>: 16 nodes/block
    const int AG64  = (NN + 31) / 32;       // gathcomb<64>: 32 nodes/block

    // Layer 1
    gemm16_k<256><<<GB, 256, 0, stream>>>(x16, Bp0, Cbuf);
    gathcomb_k<128, false><<<AG128, 256, 0, stream>>>(rowptr, csr, Cbuf, bl0, H, nullptr);
    // Layer 2
    gemm16_k<256><<<GB, 256, 0, stream>>>(H, Bp1, Cbuf);
    gathcomb_k<128, false><<<AG128, 256, 0, stream>>>(rowptr, csr, Cbuf, bl1, H, nullptr);
    // Layer 3 (+fused log_softmax)
    gemm16_k<128><<<GB, 256, 0, stream>>>(H, Bp2, Cbuf);
    gathcomb_k<64, true><<<AG64, 256, 0, stream>>>(rowptr, csr, Cbuf, bl2, nullptr, out);
}

// Round 4
// 211.359 us; speedup vs baseline: 17.3987x; 1.1401x over previous
//
#include <hip/hip_runtime.h>
#include <hip/hip_bf16.h>

#define NN 50000
#define NE 800000
#define NPAD 50048   // rows padded to multiple of 64
#define NBK 512      // coarse buckets for CSR build
#define RNG 98       // nodes per bucket (512*98 = 50176 >= NN)
#define BCAP 2560    // bucket capacity (mean 1562, ~25 sigma margin)
#define CSTRIDE 16   // cursor padding: 1 cursor per 64B line

typedef __attribute__((ext_vector_type(8))) short bf8;   // 8 bf16 = 4 VGPR
typedef __attribute__((ext_vector_type(4))) float f4;

__device__ __forceinline__ unsigned short f2bf(float f) {  // RNE
    union { float f; unsigned int u; } x; x.f = f;
    unsigned int r = x.u + 0x7fffu + ((x.u >> 16) & 1u);
    return (unsigned short)(r >> 16);
}
__device__ __forceinline__ float b2f(short s) {
    union { unsigned int u; float f; } x;
    x.u = ((unsigned int)(unsigned short)s) << 16;
    return x.f;
}

// ---------------- CSR build (two-level bucketed) ----------------

__global__ void bucket_fill_k(const int* __restrict__ ei, int* __restrict__ cursor,
                              unsigned int* __restrict__ bucket) {
    int e = blockIdx.x * 256 + threadIdx.x;
    if (e >= NE) return;
    int s = ei[e];
    int d = ei[NE + e];
    int b = d / RNG;
    int dloc = d - b * RNG;
    int pos = atomicAdd(&cursor[b * CSTRIDE], 1);
    if (pos < BCAP) bucket[(size_t)b * BCAP + pos] = (unsigned)s | ((unsigned)dloc << 16);
}

__global__ void scan512_k(const int* __restrict__ cursor, int* __restrict__ base,
                          int* __restrict__ rowptr) {
    __shared__ int s[NBK];
    int tid = threadIdx.x;
    int v = cursor[tid * CSTRIDE];
    s[tid] = v;
    __syncthreads();
    #pragma unroll
    for (int off = 1; off < NBK; off <<= 1) {
        int t = (tid >= off) ? s[tid - off] : 0;
        __syncthreads();
        s[tid] += t;
        __syncthreads();
    }
    base[tid] = s[tid] - v;
    if (tid == 0) rowptr[NN] = NE;
}

// one block per bucket: LDS histogram + rank-scatter -> contiguous csr segment + rowptr slice
__global__ __launch_bounds__(256) void csr_build_k(const unsigned int* __restrict__ bucket,
                                                   const int* __restrict__ cursor,
                                                   const int* __restrict__ base,
                                                   int* __restrict__ rowptr,
                                                   int* __restrict__ csr) {
    __shared__ unsigned int ent[BCAP];
    __shared__ int hist[RNG];
    __shared__ int lcur[RNG];
    const int b = blockIdx.x, tid = threadIdx.x;
    const int sz0 = cursor[b * CSTRIDE];
    const int sz = sz0 < BCAP ? sz0 : BCAP;
    const int gbase = base[b];
    for (int i = tid; i < RNG; i += 256) { hist[i] = 0; lcur[i] = 0; }
    __syncthreads();
    for (int i = tid; i < sz; i += 256) {
        unsigned v = bucket[(size_t)b * BCAP + i];
        ent[i] = v;
        atomicAdd(&hist[v >> 16], 1);
    }
    __syncthreads();
    if (tid == 0) {  // exclusive scan of 98 counters
        int acc = 0;
        #pragma unroll 2
        for (int i = 0; i < RNG; ++i) { int c = hist[i]; hist[i] = acc; acc += c; }
    }
    __syncthreads();
    const int n0 = b * RNG;
    for (int i = tid; i < RNG; i += 256) {
        int n = n0 + i;
        if (n < NN) rowptr[n] = gbase + hist[i];
    }
    for (int i = tid; i < sz; i += 256) {
        unsigned v = ent[i];
        int dloc = v >> 16;
        int r = atomicAdd(&lcur[dloc], 1);
        csr[gbase + hist[dloc] + r] = (int)(v & 0xffffu);
    }
}

// ---------------- pack all weights: B = [Wl | Wr] -> MFMA B-fragment layout ----------------
__global__ void pack_all_k(const float* __restrict__ Wl0, const float* __restrict__ Wr0,
                           const float* __restrict__ Wl1, const float* __restrict__ Wr1,
                           const float* __restrict__ Wl2, const float* __restrict__ Wr2,
                           unsigned short* __restrict__ Bp) {
    int idx = blockIdx.x * 256 + threadIdx.x;
    const float *Wl, *Wr;
    int Mo, local;
    unsigned short* out;
    if (idx < 32768)       { Wl = Wl0; Wr = Wr0; Mo = 128; out = Bp;         local = idx; }
    else if (idx < 65536)  { Wl = Wl1; Wr = Wr1; Mo = 128; out = Bp + 32768; local = idx - 32768; }
    else if (idx < 81920)  { Wl = Wl2; Wr = Wr2; Mo = 64;  out = Bp + 65536; local = idx - 65536; }
    else return;
    int ncol = 2 * Mo;
    int k = local / ncol, c = local % ncol;
    float v = (c < Mo) ? Wl[k * Mo + c] : Wr[k * Mo + (c - Mo)];
    int cf = c >> 4, ks = k >> 5;
    int lane = (c & 15) | (((k & 31) >> 3) << 4);
    int i = k & 7;
    out[(((cf << 2) | ks) * 64 + lane) * 8 + i] = f2bf(v);
}

// ---------------- fused dual GEMM:  C[r][0:NCOL] = A[r][0:128] @ [Wl|Wr] ----------------
template<int NCOL, bool AF32>
__global__ __launch_bounds__(256) void gemm16_k(const void* __restrict__ Av,
                                                const unsigned short* __restrict__ Bp,
                                                unsigned short* __restrict__ C) {
    constexpr int CFW = NCOL / 64;           // colfrags per wave (4 or 2)
    const int wave = threadIdx.x >> 6;
    const int lane = threadIdx.x & 63;
    const int r0 = blockIdx.x * 64;

    bf8 bfr[CFW][4];
    const bf8* bp = reinterpret_cast<const bf8*>(Bp);
    #pragma unroll
    for (int cf = 0; cf < CFW; ++cf)
        #pragma unroll
        for (int ks = 0; ks < 4; ++ks)
            bfr[cf][ks] = bp[((wave * CFW + cf) * 4 + ks) * 64 + lane];

    const int rlane = lane & 15, kc = lane >> 4;
    #pragma unroll
    for (int rf = 0; rf < 4; ++rf) {
        const int arow = r0 + rf * 16 + rlane;
        bf8 afr[4];
        if constexpr (AF32) {
            const bool ok = arow < NN;
            const float* A = (const float*)Av;
            const float4* ap = reinterpret_cast<const float4*>(A + (size_t)arow * 128);
            #pragma unroll
            for (int ks = 0; ks < 4; ++ks) {
                float4 a0 = make_float4(0.f,0.f,0.f,0.f), a1 = a0;
                if (ok) { a0 = ap[ks * 8 + kc * 2]; a1 = ap[ks * 8 + kc * 2 + 1]; }
                bf8 t;
                t[0]=(short)f2bf(a0.x); t[1]=(short)f2bf(a0.y); t[2]=(short)f2bf(a0.z); t[3]=(short)f2bf(a0.w);
                t[4]=(short)f2bf(a1.x); t[5]=(short)f2bf(a1.y); t[6]=(short)f2bf(a1.z); t[7]=(short)f2bf(a1.w);
                afr[ks] = t;
            }
        } else {
            const unsigned short* A = (const unsigned short*)Av;
            const bf8* ap = reinterpret_cast<const bf8*>(A + (size_t)arow * 128);
            #pragma unroll
            for (int ks = 0; ks < 4; ++ks) afr[ks] = ap[ks * 4 + kc];
        }
        f4 acc[CFW];
        #pragma unroll
        for (int cf = 0; cf < CFW; ++cf) acc[cf] = (f4){0.f, 0.f, 0.f, 0.f};
        #pragma unroll
        for (int ks = 0; ks < 4; ++ks)
            #pragma unroll
            for (int cf = 0; cf < CFW; ++cf)
                acc[cf] = __builtin_amdgcn_mfma_f32_16x16x32_bf16(afr[ks], bfr[cf][ks], acc[cf], 0, 0, 0);
        // D layout: col = lane&15, row = (lane>>4)*4 + j
        const int orow0 = r0 + rf * 16 + (lane >> 4) * 4;
        #pragma unroll
        for (int j = 0; j < 4; ++j) {
            const int orow = orow0 + j;
            if (orow < NN) {
                #pragma unroll
                for (int cf = 0; cf < CFW; ++cf)
                    C[(size_t)orow * NCOL + (wave * CFW + cf) * 16 + rlane] = f2bf(acc[cf][j]);
            }
        }
    }
}

// ---------------- gather + combine (+ELU or +log_softmax) ----------------
// C rows are [Y(MO cols) | Z(MO cols)].  h = mean(Y[neigh]) + Z + bias
template<int MO, bool LAST>
__global__ __launch_bounds__(256) void gathcomb_k(const int* __restrict__ rowptr,
                                                  const int* __restrict__ csr,
                                                  const unsigned short* __restrict__ C,
                                                  const float* __restrict__ bias,
                                                  unsigned short* __restrict__ Hout,
                                                  float* __restrict__ lout) {
    constexpr int NCOL = 2 * MO;
    constexpr int GSZ = MO / 8;          // lanes per node
    constexpr int NPB = 256 / GSZ;       // nodes per block
    const int g = threadIdx.x / GSZ;
    const int l = threadIdx.x % GSZ;
    const int n = blockIdx.x * NPB + g;
    if (n >= NN) return;
    const int beg = rowptr[n], end = rowptr[n + 1];

    float acc[8] = {0.f, 0.f, 0.f, 0.f, 0.f, 0.f, 0.f, 0.f};
    int e = beg;
    for (; e + 1 < end; e += 2) {
        const int s0 = csr[e], s1 = csr[e + 1];
        const bf8 v0 = *reinterpret_cast<const bf8*>(&C[(size_t)s0 * NCOL + l * 8]);
        const bf8 v1 = *reinterpret_cast<const bf8*>(&C[(size_t)s1 * NCOL + l * 8]);
        #pragma unroll
        for (int i = 0; i < 8; ++i) acc[i] += b2f(v0[i]) + b2f(v1[i]);
    }
    if (e < end) {
        const int s0 = csr[e];
        const bf8 v0 = *reinterpret_cast<const bf8*>(&C[(size_t)s0 * NCOL + l * 8]);
        #pragma unroll
        for (int i = 0; i < 8; ++i) acc[i] += b2f(v0[i]);
    }
    const float inv = 1.0f / fmaxf((float)(end - beg), 1.0f);
    const bf8 z = *reinterpret_cast<const bf8*>(&C[(size_t)n * NCOL + MO + l * 8]);
    float h[8];
    #pragma unroll
    for (int i = 0; i < 8; ++i) h[i] = acc[i] * inv + b2f(z[i]) + bias[l * 8 + i];

    if (!LAST) {
        bf8 o;
        #pragma unroll
        for (int i = 0; i < 8; ++i) {
            const float v = h[i] > 0.f ? h[i] : expf(h[i]) - 1.f;  // ELU
            o[i] = (short)f2bf(v);
        }
        *reinterpret_cast<bf8*>(&Hout[(size_t)n * MO + l * 8]) = o;
    } else {
        float m = h[0];
        #pragma unroll
        for (int i = 1; i < 8; ++i) m = fmaxf(m, h[i]);
        #pragma unroll
        for (int o = 1; o < GSZ; o <<= 1) m = fmaxf(m, __shfl_xor(m, o, 64));
        float s = 0.f;
        #pragma unroll
        for (int i = 0; i < 8; ++i) s += expf(h[i] - m);
        #pragma unroll
        for (int o = 1; o < GSZ; o <<= 1) s += __shfl_xor(s, o, 64);
        const float lg = m + logf(s);
        float4 o0, o1;
        o0.x = h[0] - lg; o0.y = h[1] - lg; o0.z = h[2] - lg; o0.w = h[3] - lg;
        o1.x = h[4] - lg; o1.y = h[5] - lg; o1.z = h[6] - lg; o1.w = h[7] - lg;
        float* op = &lout[(size_t)n * MO + l * 8];
        *reinterpret_cast<float4*>(op) = o0;
        *reinterpret_cast<float4*>(op + 4) = o1;
    }
}

extern "C" void kernel_launch(void* const* d_in, const int* in_sizes, int n_in,
                              void* d_out, int out_size, void* d_ws, size_t ws_size,
                              hipStream_t stream) {
    const float* x   = (const float*)d_in[0];
    const int*   ei  = (const int*)d_in[1];
    const float* Wl0 = (const float*)d_in[2];
    const float* bl0 = (const float*)d_in[3];
    const float* Wr0 = (const float*)d_in[4];
    const float* Wl1 = (const float*)d_in[5];
    const float* bl1 = (const float*)d_in[6];
    const float* Wr1 = (const float*)d_in[7];
    const float* Wl2 = (const float*)d_in[8];
    const float* bl2 = (const float*)d_in[9];
    const float* Wr2 = (const float*)d_in[10];
    float* out = (float*)d_out;

    unsigned short* H    = (unsigned short*)d_ws;              // [NPAD][128]
    unsigned short* Cbuf = H + (size_t)NPAD * 128;             // [NPAD][256]
    unsigned short* Bp   = Cbuf + (size_t)NPAD * 256;          // 81920
    int* rowptr = (int*)(Bp + 81920);                          // NN+1
    int* cursor = rowptr + (NN + 2);                           // NBK*CSTRIDE
    int* base   = cursor + NBK * CSTRIDE;                      // NBK
    int* csr    = base + NBK;                                  // NE
    unsigned int* bucket = (unsigned int*)(csr + NE);          // NBK*BCAP

    // ---- CSR build ----
    hipMemsetAsync(cursor, 0, NBK * CSTRIDE * sizeof(int), stream);
    bucket_fill_k<<<(NE + 255) / 256, 256, 0, stream>>>(ei, cursor, bucket);
    scan512_k<<<1, NBK, 0, stream>>>(cursor, base, rowptr);
    csr_build_k<<<NBK, 256, 0, stream>>>(bucket, cursor, base, rowptr, csr);

    // ---- pack weights ----
    pack_all_k<<<320, 256, 0, stream>>>(Wl0, Wr0, Wl1, Wr1, Wl2, Wr2, Bp);

    const int GB = NPAD / 64;               // 782
    const int AG128 = (NN + 15) / 16;
    const int AG64  = (NN + 31) / 32;

    // Layer 1 (A = fp32 x, converted in-register)
    gemm16_k<256, true><<<GB, 256, 0, stream>>>(x, Bp, Cbuf);
    gathcomb_k<128, false><<<AG128, 256, 0, stream>>>(rowptr, csr, Cbuf, bl0, H, nullptr);
    // Layer 2
    gemm16_k<256, false><<<GB, 256, 0, stream>>>(H, Bp + 32768, Cbuf);
    gathcomb_k<128, false><<<AG128, 256, 0, stream>>>(rowptr, csr, Cbuf, bl1, H, nullptr);
    // Layer 3 (+fused log_softmax)
    gemm16_k<128, false><<<GB, 256, 0, stream>>>(H, Bp + 65536, Cbuf);
    gathcomb_k<64, true><<<AG64, 256, 0, stream>>>(rowptr, csr, Cbuf, bl2, nullptr, out);
}

// Round 5
// 179.576 us; speedup vs baseline: 20.4782x; 1.1770x over previous
//
#include <hip/hip_runtime.h>
#include <hip/hip_bf16.h>

#define NN 50000
#define NE 800000
#define NPAD 50048   // rows padded to multiple of 64
#define NBK 512      // coarse buckets for CSR build
#define RNG 98       // nodes per bucket (512*98 = 50176 >= NN)
#define BCAP 2560    // bucket capacity (mean 1562)
#define CSTRIDE 16   // cursor padding: 1 cursor per 64B line
#define EPB 4096     // edges per block in bfill2
#define NFB ((NE + EPB - 1) / EPB)   // 196 blocks

typedef __attribute__((ext_vector_type(8))) short bf8;   // 8 bf16 = 4 VGPR
typedef __attribute__((ext_vector_type(4))) float f4;

__device__ __forceinline__ unsigned short f2bf(float f) {  // RNE
    union { float f; unsigned int u; } x; x.f = f;
    unsigned int r = x.u + 0x7fffu + ((x.u >> 16) & 1u);
    return (unsigned short)(r >> 16);
}
__device__ __forceinline__ float b2f(short s) {
    union { unsigned int u; float f; } x;
    x.u = ((unsigned int)(unsigned short)s) << 16;
    return x.f;
}

// ---------------- CSR build (two-level bucketed, block-aggregated fill) ----------------

// Each block: LDS histogram over 512 buckets -> one range-reserving atomic per
// (block,bucket) -> rank-scatter to LDS -> coalesced run writes.
__global__ __launch_bounds__(256) void bfill2_k(const int* __restrict__ ei,
                                                int* __restrict__ cursor,
                                                unsigned int* __restrict__ bucket) {
    __shared__ unsigned int sorted[EPB];
    __shared__ unsigned short sbuck[EPB];
    __shared__ int hist[NBK], ofs[NBK], gpos[NBK], stmp[256];
    const int tid = threadIdx.x;
    const int e0 = blockIdx.x * EPB;
    const int n = (NE - e0) < EPB ? (NE - e0) : EPB;

    for (int i = tid; i < NBK; i += 256) hist[i] = 0;
    __syncthreads();

    unsigned int ent[EPB / 256];
    short bks[EPB / 256];
    #pragma unroll
    for (int j = 0; j < EPB / 256; ++j) {
        const int li = tid + j * 256;
        int b = -1; unsigned v = 0;
        if (li < n) {
            const int e = e0 + li;
            const int s = ei[e];
            const int d = ei[NE + e];
            b = d / RNG;
            v = (unsigned)s | ((unsigned)(d - b * RNG) << 16);
            atomicAdd(&hist[b], 1);
        }
        ent[j] = v; bks[j] = (short)b;
    }
    __syncthreads();

    // exclusive scan of hist[512] using 256 threads (pairwise)
    const int p0 = hist[2 * tid], p1 = hist[2 * tid + 1];
    stmp[tid] = p0 + p1;
    __syncthreads();
    #pragma unroll
    for (int off = 1; off < 256; off <<= 1) {
        const int t = (tid >= off) ? stmp[tid - off] : 0;
        __syncthreads();
        stmp[tid] += t;
        __syncthreads();
    }
    const int pbase = stmp[tid] - p0 - p1;
    ofs[2 * tid] = pbase;
    ofs[2 * tid + 1] = pbase + p0;
    __syncthreads();

    // reserve global ranges (1 atomic per non-empty bucket per block)
    for (int i = tid; i < NBK; i += 256) {
        const int c = hist[i];
        gpos[i] = c ? atomicAdd(&cursor[i * CSTRIDE], c) : 0;
    }
    // local rank-scatter into bucket-sorted LDS order
    for (int i = tid; i < NBK; i += 256) hist[i] = ofs[i];
    __syncthreads();
    #pragma unroll
    for (int j = 0; j < EPB / 256; ++j) {
        if (bks[j] >= 0) {
            const int r = atomicAdd(&hist[(int)bks[j]], 1);
            sorted[r] = ent[j];
            sbuck[r] = (unsigned short)bks[j];
        }
    }
    __syncthreads();
    // coalesced run writes
    for (int i = tid; i < n; i += 256) {
        const int b = sbuck[i];
        const int idx = gpos[b] + (i - ofs[b]);
        if (idx < BCAP) bucket[(size_t)b * BCAP + idx] = sorted[i];
    }
}

__global__ void scan512_k(const int* __restrict__ cursor, int* __restrict__ base,
                          int* __restrict__ rowptr) {
    __shared__ int s[NBK];
    int tid = threadIdx.x;
    int v = cursor[tid * CSTRIDE];
    s[tid] = v;
    __syncthreads();
    #pragma unroll
    for (int off = 1; off < NBK; off <<= 1) {
        int t = (tid >= off) ? s[tid - off] : 0;
        __syncthreads();
        s[tid] += t;
        __syncthreads();
    }
    base[tid] = s[tid] - v;
    if (tid == 0) rowptr[NN] = NE;
}

// one block per bucket: LDS histogram + rank-scatter -> contiguous csr segment + rowptr slice
__global__ __launch_bounds__(256) void csr_build_k(const unsigned int* __restrict__ bucket,
                                                   const int* __restrict__ cursor,
                                                   const int* __restrict__ base,
                                                   int* __restrict__ rowptr,
                                                   int* __restrict__ csr) {
    __shared__ unsigned int ent[BCAP];
    __shared__ int hist[RNG];
    __shared__ int lcur[RNG];
    const int b = blockIdx.x, tid = threadIdx.x;
    const int sz0 = cursor[b * CSTRIDE];
    const int sz = sz0 < BCAP ? sz0 : BCAP;
    const int gbase = base[b];
    for (int i = tid; i < RNG; i += 256) { hist[i] = 0; lcur[i] = 0; }
    __syncthreads();
    for (int i = tid; i < sz; i += 256) {
        unsigned v = bucket[(size_t)b * BCAP + i];
        ent[i] = v;
        atomicAdd(&hist[v >> 16], 1);
    }
    __syncthreads();
    if (tid == 0) {  // exclusive scan of 98 counters
        int acc = 0;
        #pragma unroll 2
        for (int i = 0; i < RNG; ++i) { int c = hist[i]; hist[i] = acc; acc += c; }
    }
    __syncthreads();
    const int n0 = b * RNG;
    for (int i = tid; i < RNG; i += 256) {
        int n = n0 + i;
        if (n < NN) rowptr[n] = gbase + hist[i];
    }
    for (int i = tid; i < sz; i += 256) {
        unsigned v = ent[i];
        int dloc = v >> 16;
        int r = atomicAdd(&lcur[dloc], 1);
        csr[gbase + hist[dloc] + r] = (int)(v & 0xffffu);
    }
}

// ---------------- pack all weights: B = [Wl | Wr] -> MFMA B-fragment layout ----------------
__global__ void pack_all_k(const float* __restrict__ Wl0, const float* __restrict__ Wr0,
                           const float* __restrict__ Wl1, const float* __restrict__ Wr1,
                           const float* __restrict__ Wl2, const float* __restrict__ Wr2,
                           unsigned short* __restrict__ Bp) {
    int idx = blockIdx.x * 256 + threadIdx.x;
    const float *Wl, *Wr;
    int Mo, local;
    unsigned short* out;
    if (idx < 32768)       { Wl = Wl0; Wr = Wr0; Mo = 128; out = Bp;         local = idx; }
    else if (idx < 65536)  { Wl = Wl1; Wr = Wr1; Mo = 128; out = Bp + 32768; local = idx - 32768; }
    else if (idx < 81920)  { Wl = Wl2; Wr = Wr2; Mo = 64;  out = Bp + 65536; local = idx - 65536; }
    else return;
    int ncol = 2 * Mo;
    int k = local / ncol, c = local % ncol;
    float v = (c < Mo) ? Wl[k * Mo + c] : Wr[k * Mo + (c - Mo)];
    int cf = c >> 4, ks = k >> 5;
    int lane = (c & 15) | (((k & 31) >> 3) << 4);
    int i = k & 7;
    out[(((cf << 2) | ks) * 64 + lane) * 8 + i] = f2bf(v);
}

// ---------------- fused dual GEMM:  C[r][0:NCOL] = A[r][0:128] @ [Wl|Wr] ----------------
template<int NCOL, bool AF32>
__global__ __launch_bounds__(256) void gemm16_k(const void* __restrict__ Av,
                                                const unsigned short* __restrict__ Bp,
                                                unsigned short* __restrict__ C) {
    constexpr int CFW = NCOL / 64;           // colfrags per wave (4 or 2)
    const int wave = threadIdx.x >> 6;
    const int lane = threadIdx.x & 63;
    const int r0 = blockIdx.x * 64;

    bf8 bfr[CFW][4];
    const bf8* bp = reinterpret_cast<const bf8*>(Bp);
    #pragma unroll
    for (int cf = 0; cf < CFW; ++cf)
        #pragma unroll
        for (int ks = 0; ks < 4; ++ks)
            bfr[cf][ks] = bp[((wave * CFW + cf) * 4 + ks) * 64 + lane];

    const int rlane = lane & 15, kc = lane >> 4;
    #pragma unroll
    for (int rf = 0; rf < 4; ++rf) {
        const int arow = r0 + rf * 16 + rlane;
        bf8 afr[4];
        if constexpr (AF32) {
            const bool ok = arow < NN;
            const float* A = (const float*)Av;
            const float4* ap = reinterpret_cast<const float4*>(A + (size_t)arow * 128);
            #pragma unroll
            for (int ks = 0; ks < 4; ++ks) {
                float4 a0 = make_float4(0.f,0.f,0.f,0.f), a1 = a0;
                if (ok) { a0 = ap[ks * 8 + kc * 2]; a1 = ap[ks * 8 + kc * 2 + 1]; }
                bf8 t;
                t[0]=(short)f2bf(a0.x); t[1]=(short)f2bf(a0.y); t[2]=(short)f2bf(a0.z); t[3]=(short)f2bf(a0.w);
                t[4]=(short)f2bf(a1.x); t[5]=(short)f2bf(a1.y); t[6]=(short)f2bf(a1.z); t[7]=(short)f2bf(a1.w);
                afr[ks] = t;
            }
        } else {
            const unsigned short* A = (const unsigned short*)Av;
            const bf8* ap = reinterpret_cast<const bf8*>(A + (size_t)arow * 128);
            #pragma unroll
            for (int ks = 0; ks < 4; ++ks) afr[ks] = ap[ks * 4 + kc];
        }
        f4 acc[CFW];
        #pragma unroll
        for (int cf = 0; cf < CFW; ++cf) acc[cf] = (f4){0.f, 0.f, 0.f, 0.f};
        #pragma unroll
        for (int ks = 0; ks < 4; ++ks)
            #pragma unroll
            for (int cf = 0; cf < CFW; ++cf)
                acc[cf] = __builtin_amdgcn_mfma_f32_16x16x32_bf16(afr[ks], bfr[cf][ks], acc[cf], 0, 0, 0);
        // D layout: col = lane&15, row = (lane>>4)*4 + j
        const int orow0 = r0 + rf * 16 + (lane >> 4) * 4;
        #pragma unroll
        for (int j = 0; j < 4; ++j) {
            const int orow = orow0 + j;
            if (orow < NN) {
                #pragma unroll
                for (int cf = 0; cf < CFW; ++cf)
                    C[(size_t)orow * NCOL + (wave * CFW + cf) * 16 + rlane] = f2bf(acc[cf][j]);
            }
        }
    }
}

// ---------------- gather + combine (+ELU or +log_softmax) ----------------
// C rows are [Y(MO cols) | Z(MO cols)].  h = mean(Y[neigh]) + Z + bias
template<int MO, bool LAST>
__global__ __launch_bounds__(256) void gathcomb_k(const int* __restrict__ rowptr,
                                                  const int* __restrict__ csr,
                                                  const unsigned short* __restrict__ C,
                                                  const float* __restrict__ bias,
                                                  unsigned short* __restrict__ Hout,
                                                  float* __restrict__ lout) {
    constexpr int NCOL = 2 * MO;
    constexpr int GSZ = MO / 8;          // lanes per node
    constexpr int NPB = 256 / GSZ;       // nodes per block
    const int g = threadIdx.x / GSZ;
    const int l = threadIdx.x % GSZ;
    const int n = blockIdx.x * NPB + g;
    if (n >= NN) return;
    const int beg = rowptr[n], end = rowptr[n + 1];

    float acc[8] = {0.f, 0.f, 0.f, 0.f, 0.f, 0.f, 0.f, 0.f};
    int e = beg;
    for (; e + 1 < end; e += 2) {
        const int s0 = csr[e], s1 = csr[e + 1];
        const bf8 v0 = *reinterpret_cast<const bf8*>(&C[(size_t)s0 * NCOL + l * 8]);
        const bf8 v1 = *reinterpret_cast<const bf8*>(&C[(size_t)s1 * NCOL + l * 8]);
        #pragma unroll
        for (int i = 0; i < 8; ++i) acc[i] += b2f(v0[i]) + b2f(v1[i]);
    }
    if (e < end) {
        const int s0 = csr[e];
        const bf8 v0 = *reinterpret_cast<const bf8*>(&C[(size_t)s0 * NCOL + l * 8]);
        #pragma unroll
        for (int i = 0; i < 8; ++i) acc[i] += b2f(v0[i]);
    }
    const float inv = 1.0f / fmaxf((float)(end - beg), 1.0f);
    const bf8 z = *reinterpret_cast<const bf8*>(&C[(size_t)n * NCOL + MO + l * 8]);
    float h[8];
    #pragma unroll
    for (int i = 0; i < 8; ++i) h[i] = acc[i] * inv + b2f(z[i]) + bias[l * 8 + i];

    if (!LAST) {
        bf8 o;
        #pragma unroll
        for (int i = 0; i < 8; ++i) {
            const float v = h[i] > 0.f ? h[i] : expf(h[i]) - 1.f;  // ELU
            o[i] = (short)f2bf(v);
        }
        *reinterpret_cast<bf8*>(&Hout[(size_t)n * MO + l * 8]) = o;
    } else {
        float m = h[0];
        #pragma unroll
        for (int i = 1; i < 8; ++i) m = fmaxf(m, h[i]);
        #pragma unroll
        for (int o = 1; o < GSZ; o <<= 1) m = fmaxf(m, __shfl_xor(m, o, 64));
        float s = 0.f;
        #pragma unroll
        for (int i = 0; i < 8; ++i) s += expf(h[i] - m);
        #pragma unroll
        for (int o = 1; o < GSZ; o <<= 1) s += __shfl_xor(s, o, 64);
        const float lg = m + logf(s);
        float4 o0, o1;
        o0.x = h[0] - lg; o0.y = h[1] - lg; o0.z = h[2] - lg; o0.w = h[3] - lg;
        o1.x = h[4] - lg; o1.y = h[5] - lg; o1.z = h[6] - lg; o1.w = h[7] - lg;
        float* op = &lout[(size_t)n * MO + l * 8];
        *reinterpret_cast<float4*>(op) = o0;
        *reinterpret_cast<float4*>(op + 4) = o1;
    }
}

extern "C" void kernel_launch(void* const* d_in, const int* in_sizes, int n_in,
                              void* d_out, int out_size, void* d_ws, size_t ws_size,
                              hipStream_t stream) {
    const float* x   = (const float*)d_in[0];
    const int*   ei  = (const int*)d_in[1];
    const float* Wl0 = (const float*)d_in[2];
    const float* bl0 = (const float*)d_in[3];
    const float* Wr0 = (const float*)d_in[4];
    const float* Wl1 = (const float*)d_in[5];
    const float* bl1 = (const float*)d_in[6];
    const float* Wr1 = (const float*)d_in[7];
    const float* Wl2 = (const float*)d_in[8];
    const float* bl2 = (const float*)d_in[9];
    const float* Wr2 = (const float*)d_in[10];
    float* out = (float*)d_out;

    unsigned short* H    = (unsigned short*)d_ws;              // [NPAD][128]
    unsigned short* Cbuf = H + (size_t)NPAD * 128;             // [NPAD][256]
    unsigned short* Bp   = Cbuf + (size_t)NPAD * 256;          // 81920
    int* rowptr = (int*)(Bp + 81920);                          // NN+1
    int* cursor = rowptr + (NN + 2);                           // NBK*CSTRIDE
    int* base   = cursor + NBK * CSTRIDE;                      // NBK
    int* csr    = base + NBK;                                  // NE
    unsigned int* bucket = (unsigned int*)(csr + NE);          // NBK*BCAP

    // ---- CSR build ----
    hipMemsetAsync(cursor, 0, NBK * CSTRIDE * sizeof(int), stream);
    bfill2_k<<<NFB, 256, 0, stream>>>(ei, cursor, bucket);
    scan512_k<<<1, NBK, 0, stream>>>(cursor, base, rowptr);
    csr_build_k<<<NBK, 256, 0, stream>>>(bucket, cursor, base, rowptr, csr);

    // ---- pack weights ----
    pack_all_k<<<320, 256, 0, stream>>>(Wl0, Wr0, Wl1, Wr1, Wl2, Wr2, Bp);

    const int GB = NPAD / 64;               // 782
    const int AG128 = (NN + 15) / 16;
    const int AG64  = (NN + 31) / 32;

    // Layer 1 (A = fp32 x, converted in-register)
    gemm16_k<256, true><<<GB, 256, 0, stream>>>(x, Bp, Cbuf);
    gathcomb_k<128, false><<<AG128, 256, 0, stream>>>(rowptr, csr, Cbuf, bl0, H, nullptr);
    // Layer 2
    gemm16_k<256, false><<<GB, 256, 0, stream>>>(H, Bp + 32768, Cbuf);
    gathcomb_k<128, false><<<AG128, 256, 0, stream>>>(rowptr, csr, Cbuf, bl1, H, nullptr);
    // Layer 3 (+fused log_softmax)
    gemm16_k<128, false><<<GB, 256, 0, stream>>>(H, Bp + 65536, Cbuf);
    gathcomb_k<64, true><<<AG64, 256, 0, stream>>>(rowptr, csr, Cbuf, bl2, nullptr, out);
}

// Round 6
// 172.206 us; speedup vs baseline: 21.3546x; 1.0428x over previous
//
#include <hip/hip_runtime.h>
#include <hip/hip_bf16.h>

#define NN 50000
#define NE 800000
#define NPAD 50048   // rows padded to multiple of 64
#define NBK 512      // coarse buckets for CSR build
#define RNG 98       // nodes per bucket (512*98 = 50176 >= NN)
#define BCAP 2560    // bucket capacity (mean 1568, ~25 sigma margin)
#define CSTRIDE 16   // cursor padding: 1 cursor per 64B line
#define EPB 4096     // edges per block in bfill2
#define NFB ((NE + EPB - 1) / EPB)   // 196 blocks

typedef __attribute__((ext_vector_type(8))) short bf8;   // 8 bf16 = 4 VGPR
typedef __attribute__((ext_vector_type(4))) float f4;

__device__ __forceinline__ unsigned short f2bf(float f) {  // RNE
    union { float f; unsigned int u; } x; x.f = f;
    unsigned int r = x.u + 0x7fffu + ((x.u >> 16) & 1u);
    return (unsigned short)(r >> 16);
}
__device__ __forceinline__ float b2f(short s) {
    union { unsigned int u; float f; } x;
    x.u = ((unsigned int)(unsigned short)s) << 16;
    return x.f;
}

// ---------------- pack all weights (+ zero bucket cursors) ----------------
// B = [Wl | Wr] -> MFMA B-fragment layout. Runs FIRST each call; block 0 also
// zeroes the 512 bucket cursors (replaces a 42us fillBufferAligned graph node).
__global__ void pack_all_k(const float* __restrict__ Wl0, const float* __restrict__ Wr0,
                           const float* __restrict__ Wl1, const float* __restrict__ Wr1,
                           const float* __restrict__ Wl2, const float* __restrict__ Wr2,
                           unsigned short* __restrict__ Bp, int* __restrict__ cursor) {
    int idx = blockIdx.x * 256 + threadIdx.x;
    if (blockIdx.x == 0) {
        #pragma unroll
        for (int i = 0; i < 2; ++i) {
            int b = threadIdx.x + i * 256;
            cursor[b * CSTRIDE] = 0;
        }
    }
    const float *Wl, *Wr;
    int Mo, local;
    unsigned short* out;
    if (idx < 32768)       { Wl = Wl0; Wr = Wr0; Mo = 128; out = Bp;         local = idx; }
    else if (idx < 65536)  { Wl = Wl1; Wr = Wr1; Mo = 128; out = Bp + 32768; local = idx - 32768; }
    else if (idx < 81920)  { Wl = Wl2; Wr = Wr2; Mo = 64;  out = Bp + 65536; local = idx - 65536; }
    else return;
    int ncol = 2 * Mo;
    int k = local / ncol, c = local % ncol;
    float v = (c < Mo) ? Wl[k * Mo + c] : Wr[k * Mo + (c - Mo)];
    int cf = c >> 4, ks = k >> 5;
    int lane = (c & 15) | (((k & 31) >> 3) << 4);
    int i = k & 7;
    out[(((cf << 2) | ks) * 64 + lane) * 8 + i] = f2bf(v);
}

// ---------------- CSR build (two-level bucketed, block-aggregated fill) ----------------

__global__ __launch_bounds__(256) void bfill2_k(const int* __restrict__ ei,
                                                int* __restrict__ cursor,
                                                unsigned int* __restrict__ bucket) {
    __shared__ unsigned int sorted[EPB];
    __shared__ unsigned short sbuck[EPB];
    __shared__ int hist[NBK], ofs[NBK], gpos[NBK], stmp[256];
    const int tid = threadIdx.x;
    const int e0 = blockIdx.x * EPB;
    const int n = (NE - e0) < EPB ? (NE - e0) : EPB;

    for (int i = tid; i < NBK; i += 256) hist[i] = 0;
    __syncthreads();

    unsigned int ent[EPB / 256];
    short bks[EPB / 256];
    #pragma unroll
    for (int j = 0; j < EPB / 256; ++j) {
        const int li = tid + j * 256;
        int b = -1; unsigned v = 0;
        if (li < n) {
            const int e = e0 + li;
            const int s = ei[e];
            const int d = ei[NE + e];
            b = d / RNG;
            v = (unsigned)s | ((unsigned)(d - b * RNG) << 16);
            atomicAdd(&hist[b], 1);
        }
        ent[j] = v; bks[j] = (short)b;
    }
    __syncthreads();

    // exclusive scan of hist[512] with 256 threads (pairwise)
    const int p0 = hist[2 * tid], p1 = hist[2 * tid + 1];
    stmp[tid] = p0 + p1;
    __syncthreads();
    #pragma unroll
    for (int off = 1; off < 256; off <<= 1) {
        const int t = (tid >= off) ? stmp[tid - off] : 0;
        __syncthreads();
        stmp[tid] += t;
        __syncthreads();
    }
    const int pbase = stmp[tid] - p0 - p1;
    ofs[2 * tid] = pbase;
    ofs[2 * tid + 1] = pbase + p0;
    __syncthreads();

    // reserve global ranges (1 atomic per non-empty bucket per block)
    for (int i = tid; i < NBK; i += 256) {
        const int c = hist[i];
        gpos[i] = c ? atomicAdd(&cursor[i * CSTRIDE], c) : 0;
    }
    // local rank-scatter into bucket-sorted LDS order
    for (int i = tid; i < NBK; i += 256) hist[i] = ofs[i];
    __syncthreads();
    #pragma unroll
    for (int j = 0; j < EPB / 256; ++j) {
        if (bks[j] >= 0) {
            const int r = atomicAdd(&hist[(int)bks[j]], 1);
            sorted[r] = ent[j];
            sbuck[r] = (unsigned short)bks[j];
        }
    }
    __syncthreads();
    // coalesced run writes
    for (int i = tid; i < n; i += 256) {
        const int b = sbuck[i];
        const int idx = gpos[b] + (i - ofs[b]);
        if (idx < BCAP) bucket[(size_t)b * BCAP + idx] = sorted[i];
    }
}

// one block per bucket: in-block 512-scan (replaces scan512_k) + LDS histogram
// + rank-scatter -> contiguous csr segment + rowptr slice
__global__ __launch_bounds__(256) void csr_build_k(const unsigned int* __restrict__ bucket,
                                                   const int* __restrict__ cursor,
                                                   int* __restrict__ rowptr,
                                                   int* __restrict__ csr) {
    __shared__ unsigned int ent[BCAP];
    __shared__ int hist[RNG];
    __shared__ int lcur[RNG];
    __shared__ int sofs[NBK], stmp[256];
    const int b = blockIdx.x, tid = threadIdx.x;

    // exclusive scan of all 512 bucket sizes (each block does its own copy)
    const int c0 = cursor[(2 * tid) * CSTRIDE];
    const int c1 = cursor[(2 * tid + 1) * CSTRIDE];
    stmp[tid] = c0 + c1;
    __syncthreads();
    #pragma unroll
    for (int off = 1; off < 256; off <<= 1) {
        const int t = (tid >= off) ? stmp[tid - off] : 0;
        __syncthreads();
        stmp[tid] += t;
        __syncthreads();
    }
    const int pbase = stmp[tid] - c0 - c1;
    sofs[2 * tid] = pbase;
    sofs[2 * tid + 1] = pbase + c0;
    for (int i = tid; i < RNG; i += 256) { hist[i] = 0; lcur[i] = 0; }
    __syncthreads();

    const int sz0 = cursor[b * CSTRIDE];
    const int sz = sz0 < BCAP ? sz0 : BCAP;
    const int gbase = sofs[b];
    for (int i = tid; i < sz; i += 256) {
        unsigned v = bucket[(size_t)b * BCAP + i];
        ent[i] = v;
        atomicAdd(&hist[v >> 16], 1);
    }
    if (b == 0 && tid == 0) rowptr[NN] = NE;
    __syncthreads();
    if (tid == 0) {  // exclusive scan of 98 counters
        int acc = 0;
        #pragma unroll 2
        for (int i = 0; i < RNG; ++i) { int c = hist[i]; hist[i] = acc; acc += c; }
    }
    __syncthreads();
    const int n0 = b * RNG;
    for (int i = tid; i < RNG; i += 256) {
        int n = n0 + i;
        if (n < NN) rowptr[n] = gbase + hist[i];
    }
    for (int i = tid; i < sz; i += 256) {
        unsigned v = ent[i];
        int dloc = v >> 16;
        int r = atomicAdd(&lcur[dloc], 1);
        csr[gbase + hist[dloc] + r] = (int)(v & 0xffffu);
    }
}

// ---------------- fused dual GEMM:  C[r][0:NCOL] = A[r][0:128] @ [Wl|Wr] ----------------
template<int NCOL, bool AF32>
__global__ __launch_bounds__(256) void gemm16_k(const void* __restrict__ Av,
                                                const unsigned short* __restrict__ Bp,
                                                unsigned short* __restrict__ C) {
    constexpr int CFW = NCOL / 64;           // colfrags per wave (4 or 2)
    const int wave = threadIdx.x >> 6;
    const int lane = threadIdx.x & 63;
    const int r0 = blockIdx.x * 64;

    bf8 bfr[CFW][4];
    const bf8* bp = reinterpret_cast<const bf8*>(Bp);
    #pragma unroll
    for (int cf = 0; cf < CFW; ++cf)
        #pragma unroll
        for (int ks = 0; ks < 4; ++ks)
            bfr[cf][ks] = bp[((wave * CFW + cf) * 4 + ks) * 64 + lane];

    const int rlane = lane & 15, kc = lane >> 4;
    #pragma unroll
    for (int rf = 0; rf < 4; ++rf) {
        const int arow = r0 + rf * 16 + rlane;
        bf8 afr[4];
        if constexpr (AF32) {
            const bool ok = arow < NN;
            const float* A = (const float*)Av;
            const float4* ap = reinterpret_cast<const float4*>(A + (size_t)arow * 128);
            #pragma unroll
            for (int ks = 0; ks < 4; ++ks) {
                float4 a0 = make_float4(0.f,0.f,0.f,0.f), a1 = a0;
                if (ok) { a0 = ap[ks * 8 + kc * 2]; a1 = ap[ks * 8 + kc * 2 + 1]; }
                bf8 t;
                t[0]=(short)f2bf(a0.x); t[1]=(short)f2bf(a0.y); t[2]=(short)f2bf(a0.z); t[3]=(short)f2bf(a0.w);
                t[4]=(short)f2bf(a1.x); t[5]=(short)f2bf(a1.y); t[6]=(short)f2bf(a1.z); t[7]=(short)f2bf(a1.w);
                afr[ks] = t;
            }
        } else {
            const unsigned short* A = (const unsigned short*)Av;
            const bf8* ap = reinterpret_cast<const bf8*>(A + (size_t)arow * 128);
            #pragma unroll
            for (int ks = 0; ks < 4; ++ks) afr[ks] = ap[ks * 4 + kc];
        }
        f4 acc[CFW];
        #pragma unroll
        for (int cf = 0; cf < CFW; ++cf) acc[cf] = (f4){0.f, 0.f, 0.f, 0.f};
        #pragma unroll
        for (int ks = 0; ks < 4; ++ks)
            #pragma unroll
            for (int cf = 0; cf < CFW; ++cf)
                acc[cf] = __builtin_amdgcn_mfma_f32_16x16x32_bf16(afr[ks], bfr[cf][ks], acc[cf], 0, 0, 0);
        // D layout: col = lane&15, row = (lane>>4)*4 + j
        const int orow0 = r0 + rf * 16 + (lane >> 4) * 4;
        #pragma unroll
        for (int j = 0; j < 4; ++j) {
            const int orow = orow0 + j;
            if (orow < NN) {
                #pragma unroll
                for (int cf = 0; cf < CFW; ++cf)
                    C[(size_t)orow * NCOL + (wave * CFW + cf) * 16 + rlane] = f2bf(acc[cf][j]);
            }
        }
    }
}

// ---------------- gather + combine (+ELU or +log_softmax) ----------------
// C rows are [Y(MO cols) | Z(MO cols)].  h = mean(Y[neigh]) + Z + bias
template<int MO, bool LAST>
__global__ __launch_bounds__(256) void gathcomb_k(const int* __restrict__ rowptr,
                                                  const int* __restrict__ csr,
                                                  const unsigned short* __restrict__ C,
                                                  const float* __restrict__ bias,
                                                  unsigned short* __restrict__ Hout,
                                                  float* __restrict__ lout) {
    constexpr int NCOL = 2 * MO;
    constexpr int GSZ = MO / 8;          // lanes per node
    constexpr int NPB = 256 / GSZ;       // nodes per block
    const int g = threadIdx.x / GSZ;
    const int l = threadIdx.x % GSZ;
    const int n = blockIdx.x * NPB + g;
    if (n >= NN) return;
    const int beg = rowptr[n], end = rowptr[n + 1];

    float acc[8] = {0.f, 0.f, 0.f, 0.f, 0.f, 0.f, 0.f, 0.f};
    int e = beg;
    for (; e + 1 < end; e += 2) {
        const int s0 = csr[e], s1 = csr[e + 1];
        const bf8 v0 = *reinterpret_cast<const bf8*>(&C[(size_t)s0 * NCOL + l * 8]);
        const bf8 v1 = *reinterpret_cast<const bf8*>(&C[(size_t)s1 * NCOL + l * 8]);
        #pragma unroll
        for (int i = 0; i < 8; ++i) acc[i] += b2f(v0[i]) + b2f(v1[i]);
    }
    if (e < end) {
        const int s0 = csr[e];
        const bf8 v0 = *reinterpret_cast<const bf8*>(&C[(size_t)s0 * NCOL + l * 8]);
        #pragma unroll
        for (int i = 0; i < 8; ++i) acc[i] += b2f(v0[i]);
    }
    const float inv = 1.0f / fmaxf((float)(end - beg), 1.0f);
    const bf8 z = *reinterpret_cast<const bf8*>(&C[(size_t)n * NCOL + MO + l * 8]);
    float h[8];
    #pragma unroll
    for (int i = 0; i < 8; ++i) h[i] = acc[i] * inv + b2f(z[i]) + bias[l * 8 + i];

    if (!LAST) {
        bf8 o;
        #pragma unroll
        for (int i = 0; i < 8; ++i) {
            const float v = h[i] > 0.f ? h[i] : expf(h[i]) - 1.f;  // ELU
            o[i] = (short)f2bf(v);
        }
        *reinterpret_cast<bf8*>(&Hout[(size_t)n * MO + l * 8]) = o;
    } else {
        float m = h[0];
        #pragma unroll
        for (int i = 1; i < 8; ++i) m = fmaxf(m, h[i]);
        #pragma unroll
        for (int o = 1; o < GSZ; o <<= 1) m = fmaxf(m, __shfl_xor(m, o, 64));
        float s = 0.f;
        #pragma unroll
        for (int i = 0; i < 8; ++i) s += expf(h[i] - m);
        #pragma unroll
        for (int o = 1; o < GSZ; o <<= 1) s += __shfl_xor(s, o, 64);
        const float lg = m + logf(s);
        float4 o0, o1;
        o0.x = h[0] - lg; o0.y = h[1] - lg; o0.z = h[2] - lg; o0.w = h[3] - lg;
        o1.x = h[4] - lg; o1.y = h[5] - lg; o1.z = h[6] - lg; o1.w = h[7] - lg;
        float* op = &lout[(size_t)n * MO + l * 8];
        *reinterpret_cast<float4*>(op) = o0;
        *reinterpret_cast<float4*>(op + 4) = o1;
    }
}

extern "C" void kernel_launch(void* const* d_in, const int* in_sizes, int n_in,
                              void* d_out, int out_size, void* d_ws, size_t ws_size,
                              hipStream_t stream) {
    const float* x   = (const float*)d_in[0];
    const int*   ei  = (const int*)d_in[1];
    const float* Wl0 = (const float*)d_in[2];
    const float* bl0 = (const float*)d_in[3];
    const float* Wr0 = (const float*)d_in[4];
    const float* Wl1 = (const float*)d_in[5];
    const float* bl1 = (const float*)d_in[6];
    const float* Wr1 = (const float*)d_in[7];
    const float* Wl2 = (const float*)d_in[8];
    const float* bl2 = (const float*)d_in[9];
    const float* Wr2 = (const float*)d_in[10];
    float* out = (float*)d_out;

    unsigned short* H    = (unsigned short*)d_ws;              // [NPAD][128]
    unsigned short* Cbuf = H + (size_t)NPAD * 128;             // [NPAD][256]
    unsigned short* Bp   = Cbuf + (size_t)NPAD * 256;          // 81920
    int* rowptr = (int*)(Bp + 81920);                          // NN+1
    int* cursor = rowptr + (NN + 2);                           // NBK*CSTRIDE
    int* csr    = cursor + NBK * CSTRIDE;                      // NE
    unsigned int* bucket = (unsigned int*)(csr + NE);          // NBK*BCAP

    // ---- pack weights + zero cursors (replaces hipMemsetAsync graph node) ----
    pack_all_k<<<320, 256, 0, stream>>>(Wl0, Wr0, Wl1, Wr1, Wl2, Wr2, Bp, cursor);

    // ---- CSR build ----
    bfill2_k<<<NFB, 256, 0, stream>>>(ei, cursor, bucket);
    csr_build_k<<<NBK, 256, 0, stream>>>(bucket, cursor, rowptr, csr);

    const int GB = NPAD / 64;               // 782
    const int AG128 = (NN + 15) / 16;
    const int AG64  = (NN + 31) / 32;

    // Layer 1 (A = fp32 x, converted in-register)
    gemm16_k<256, true><<<GB, 256, 0, stream>>>(x, Bp, Cbuf);
    gathcomb_k<128, false><<<AG128, 256, 0, stream>>>(rowptr, csr, Cbuf, bl0, H, nullptr);
    // Layer 2
    gemm16_k<256, false><<<GB, 256, 0, stream>>>(H, Bp + 32768, Cbuf);
    gathcomb_k<128, false><<<AG128, 256, 0, stream>>>(rowptr, csr, Cbuf, bl1, H, nullptr);
    // Layer 3 (+fused log_softmax)
    gemm16_k<128, false><<<GB, 256, 0, stream>>>(H, Bp + 65536, Cbuf);
    gathcomb_k<64, true><<<AG64, 256, 0, stream>>>(rowptr, csr, Cbuf, bl2, nullptr, out);
}

// Round 7
// 157.981 us; speedup vs baseline: 23.2774x; 1.0900x over previous
//
#include <hip/hip_runtime.h>
#include <hip/hip_bf16.h>

#define NN 50000
#define NE 800000
#define NPAD 50048   // rows padded to multiple of 64
#define NBK 512      // coarse buckets for CSR build
#define RNG 98       // nodes per bucket (512*98 = 50176 >= NN)
#define BCAP 2560    // bucket capacity (mean 1568)
#define CSTRIDE 16   // cursor padding: 1 cursor per 64B line
#define EPB 4096     // edges per block in bfill2
#define NFB ((NE + EPB - 1) / EPB)   // 196 blocks
#define CSRCAP 1536  // per-64-node-block CSR window (mean 1024, +16 sigma)
#define GB (NPAD / 64)               // 782 row-blocks

typedef __attribute__((ext_vector_type(8))) short bf8;   // 8 bf16 = 4 VGPR
typedef __attribute__((ext_vector_type(4))) float f4;

__device__ __forceinline__ unsigned short f2bf(float f) {  // RNE
    union { float f; unsigned int u; } x; x.f = f;
    unsigned int r = x.u + 0x7fffu + ((x.u >> 16) & 1u);
    return (unsigned short)(r >> 16);
}
__device__ __forceinline__ float b2f(short s) {
    union { unsigned int u; float f; } x;
    x.u = ((unsigned int)(unsigned short)s) << 16;
    return x.f;
}

// ---------------- launch 1: zero bucket cursors ----------------
__global__ void zero_k(int* __restrict__ cursor, int* __restrict__ rowptr) {
    cursor[threadIdx.x * CSTRIDE] = 0;
    if (threadIdx.x == 0) rowptr[NN] = NE;
}

// ---------------- launch 2: bfill2 (blocks 0..NFB-1) || pack weights (rest) ----------------
__global__ __launch_bounds__(256) void prep_k(const int* __restrict__ ei,
                                              int* __restrict__ cursor,
                                              unsigned int* __restrict__ bucket,
                                              const float* __restrict__ Wl0, const float* __restrict__ Wr0,
                                              const float* __restrict__ Wl1, const float* __restrict__ Wr1,
                                              const float* __restrict__ Wl2, const float* __restrict__ Wr2,
                                              unsigned short* __restrict__ Bp) {
    __shared__ unsigned int sorted[EPB];
    __shared__ unsigned short sbuck[EPB];
    __shared__ int hist[NBK], ofs[NBK], gpos[NBK], stmp[256];
    const int tid = threadIdx.x;
    if (blockIdx.x >= NFB) {
        // ---- weight pack: B = [Wl | Wr] -> MFMA B-fragment layout ----
        int idx = (blockIdx.x - NFB) * 256 + tid;
        const float *Wl, *Wr;
        int Mo, local;
        unsigned short* out;
        if (idx < 32768)       { Wl = Wl0; Wr = Wr0; Mo = 128; out = Bp;         local = idx; }
        else if (idx < 65536)  { Wl = Wl1; Wr = Wr1; Mo = 128; out = Bp + 32768; local = idx - 32768; }
        else if (idx < 81920)  { Wl = Wl2; Wr = Wr2; Mo = 64;  out = Bp + 65536; local = idx - 65536; }
        else return;
        int ncol = 2 * Mo;
        int k = local / ncol, c = local % ncol;
        float v = (c < Mo) ? Wl[k * Mo + c] : Wr[k * Mo + (c - Mo)];
        int cf = c >> 4, ks = k >> 5;
        int lane = (c & 15) | (((k & 31) >> 3) << 4);
        int i = k & 7;
        out[(((cf << 2) | ks) * 64 + lane) * 8 + i] = f2bf(v);
        return;
    }
    // ---- block-aggregated bucket fill ----
    const int e0 = blockIdx.x * EPB;
    const int n = (NE - e0) < EPB ? (NE - e0) : EPB;

    for (int i = tid; i < NBK; i += 256) hist[i] = 0;
    __syncthreads();

    unsigned int ent[EPB / 256];
    short bks[EPB / 256];
    #pragma unroll
    for (int j = 0; j < EPB / 256; ++j) {
        const int li = tid + j * 256;
        int b = -1; unsigned v = 0;
        if (li < n) {
            const int e = e0 + li;
            const int s = ei[e];
            const int d = ei[NE + e];
            b = d / RNG;
            v = (unsigned)s | ((unsigned)(d - b * RNG) << 16);
            atomicAdd(&hist[b], 1);
        }
        ent[j] = v; bks[j] = (short)b;
    }
    __syncthreads();

    const int p0 = hist[2 * tid], p1 = hist[2 * tid + 1];
    stmp[tid] = p0 + p1;
    __syncthreads();
    #pragma unroll
    for (int off = 1; off < 256; off <<= 1) {
        const int t = (tid >= off) ? stmp[tid - off] : 0;
        __syncthreads();
        stmp[tid] += t;
        __syncthreads();
    }
    const int pbase = stmp[tid] - p0 - p1;
    ofs[2 * tid] = pbase;
    ofs[2 * tid + 1] = pbase + p0;
    __syncthreads();

    for (int i = tid; i < NBK; i += 256) {
        const int c = hist[i];
        gpos[i] = c ? atomicAdd(&cursor[i * CSTRIDE], c) : 0;
    }
    for (int i = tid; i < NBK; i += 256) hist[i] = ofs[i];
    __syncthreads();
    #pragma unroll
    for (int j = 0; j < EPB / 256; ++j) {
        if (bks[j] >= 0) {
            const int r = atomicAdd(&hist[(int)bks[j]], 1);
            sorted[r] = ent[j];
            sbuck[r] = (unsigned short)bks[j];
        }
    }
    __syncthreads();
    for (int i = tid; i < n; i += 256) {
        const int b = sbuck[i];
        const int idx = gpos[b] + (i - ofs[b]);
        if (idx < BCAP) bucket[(size_t)b * BCAP + idx] = sorted[i];
    }
}

// ---------------- launch 3: csr_build (blocks 0..511) || layer-1 GEMM from fp32 x ----------------
__global__ __launch_bounds__(256) void mid_k(const unsigned int* __restrict__ bucket,
                                             const int* __restrict__ cursor,
                                             int* __restrict__ rowptr, int* __restrict__ csr,
                                             const float* __restrict__ x,
                                             const unsigned short* __restrict__ Bp,
                                             unsigned short* __restrict__ C) {
    __shared__ unsigned int ent[BCAP];
    __shared__ int hist[RNG], lcur[RNG], sofs[NBK], stmp[256];
    const int tid = threadIdx.x;
    if (blockIdx.x < NBK) {
        // ---- csr_build for bucket b ----
        const int b = blockIdx.x;
        const int c0 = cursor[(2 * tid) * CSTRIDE];
        const int c1 = cursor[(2 * tid + 1) * CSTRIDE];
        stmp[tid] = c0 + c1;
        __syncthreads();
        #pragma unroll
        for (int off = 1; off < 256; off <<= 1) {
            const int t = (tid >= off) ? stmp[tid - off] : 0;
            __syncthreads();
            stmp[tid] += t;
            __syncthreads();
        }
        const int pbase = stmp[tid] - c0 - c1;
        sofs[2 * tid] = pbase;
        sofs[2 * tid + 1] = pbase + c0;
        for (int i = tid; i < RNG; i += 256) { hist[i] = 0; lcur[i] = 0; }
        __syncthreads();

        const int sz0 = cursor[b * CSTRIDE];
        const int sz = sz0 < BCAP ? sz0 : BCAP;
        const int gbase = sofs[b];
        for (int i = tid; i < sz; i += 256) {
            unsigned v = bucket[(size_t)b * BCAP + i];
            ent[i] = v;
            atomicAdd(&hist[v >> 16], 1);
        }
        __syncthreads();
        if (tid == 0) {
            int acc = 0;
            #pragma unroll 2
            for (int i = 0; i < RNG; ++i) { int c = hist[i]; hist[i] = acc; acc += c; }
        }
        __syncthreads();
        const int n0 = b * RNG;
        for (int i = tid; i < RNG; i += 256) {
            int nn = n0 + i;
            if (nn < NN) rowptr[nn] = gbase + hist[i];
        }
        for (int i = tid; i < sz; i += 256) {
            unsigned v = ent[i];
            int dloc = v >> 16;
            int r = atomicAdd(&lcur[dloc], 1);
            csr[gbase + hist[dloc] + r] = (int)(v & 0xffffu);
        }
        return;
    }
    // ---- layer-1 dual GEMM: C = [x@Wl0 | x@Wr0], A fp32 converted in-register ----
    const int wave = tid >> 6;
    const int lane = tid & 63;
    const int r0 = (blockIdx.x - NBK) * 64;

    bf8 bfr[4][4];
    const bf8* bp = reinterpret_cast<const bf8*>(Bp);
    #pragma unroll
    for (int cf = 0; cf < 4; ++cf)
        #pragma unroll
        for (int ks = 0; ks < 4; ++ks)
            bfr[cf][ks] = bp[((wave * 4 + cf) * 4 + ks) * 64 + lane];

    const int rlane = lane & 15, kc = lane >> 4;
    #pragma unroll
    for (int rf = 0; rf < 4; ++rf) {
        const int arow = r0 + rf * 16 + rlane;
        const bool ok = arow < NN;
        const float4* ap = reinterpret_cast<const float4*>(x + (size_t)arow * 128);
        bf8 afr[4];
        #pragma unroll
        for (int ks = 0; ks < 4; ++ks) {
            float4 a0 = make_float4(0.f,0.f,0.f,0.f), a1 = a0;
            if (ok) { a0 = ap[ks * 8 + kc * 2]; a1 = ap[ks * 8 + kc * 2 + 1]; }
            bf8 t;
            t[0]=(short)f2bf(a0.x); t[1]=(short)f2bf(a0.y); t[2]=(short)f2bf(a0.z); t[3]=(short)f2bf(a0.w);
            t[4]=(short)f2bf(a1.x); t[5]=(short)f2bf(a1.y); t[6]=(short)f2bf(a1.z); t[7]=(short)f2bf(a1.w);
            afr[ks] = t;
        }
        f4 acc[4];
        #pragma unroll
        for (int cf = 0; cf < 4; ++cf) acc[cf] = (f4){0.f, 0.f, 0.f, 0.f};
        #pragma unroll
        for (int ks = 0; ks < 4; ++ks)
            #pragma unroll
            for (int cf = 0; cf < 4; ++cf)
                acc[cf] = __builtin_amdgcn_mfma_f32_16x16x32_bf16(afr[ks], bfr[cf][ks], acc[cf], 0, 0, 0);
        const int orow0 = r0 + rf * 16 + (lane >> 4) * 4;
        #pragma unroll
        for (int j = 0; j < 4; ++j) {
            const int orow = orow0 + j;
            if (orow < NN) {
                #pragma unroll
                for (int cf = 0; cf < 4; ++cf)
                    C[(size_t)orow * 256 + (wave * 4 + cf) * 16 + rlane] = f2bf(acc[cf][j]);
            }
        }
    }
}

// ---------------- launches 4,5: fused gather+combine+ELU+GEMM ----------------
// Cin rows are [Y(128) | Z(128)] bf16.  Per block: 64 nodes.
// Phase A: h = ELU(mean(Y[neigh]) + Z + bias) -> XOR-swizzled LDS tile [64][128] bf16.
// Phase B: Cout rows = h @ [Wl|Wr] via MFMA (A-fragments from LDS).
template<int NCOLOUT>
__global__ __launch_bounds__(256) void fused_k(const int* __restrict__ rowptr,
                                               const int* __restrict__ csr,
                                               const unsigned short* __restrict__ Cin,
                                               const float* __restrict__ bias,
                                               const unsigned short* __restrict__ Bp,
                                               unsigned short* __restrict__ Cout) {
    constexpr int CFW = NCOLOUT / 64;      // col-frags per wave (4 or 2)
    __shared__ int lcsr[CSRCAP];
    __shared__ unsigned short tile[64 * 128];  // XOR-swizzled: byte ^= (row&7)<<4
    const int tid = threadIdx.x;
    const int n0 = blockIdx.x * 64;
    const int nend = (n0 + 64 > NN) ? NN : (n0 + 64);
    const int beg0 = rowptr[n0];
    const int tot = rowptr[nend] - beg0;
    const bool inlds = tot <= CSRCAP;
    if (inlds) for (int i = tid; i < tot; i += 256) lcsr[i] = csr[beg0 + i];
    __syncthreads();

    // ---- phase A: gather (4 lanes per node, 8 independent 16B loads in flight) ----
    const int g = tid >> 2, l = tid & 3;
    const int node = n0 + g;
    char* tbase = reinterpret_cast<char*>(tile);
    if (node < NN) {
        const int beg = rowptr[node], end = rowptr[node + 1];
        float acc[32];
        #pragma unroll
        for (int i = 0; i < 32; ++i) acc[i] = 0.f;
        int e = beg;
        for (; e + 1 < end; e += 2) {
            const int s0 = inlds ? lcsr[e - beg0] : csr[e];
            const int s1 = inlds ? lcsr[e + 1 - beg0] : csr[e + 1];
            const bf8* p0 = reinterpret_cast<const bf8*>(&Cin[(size_t)s0 * 256 + l * 32]);
            const bf8* p1 = reinterpret_cast<const bf8*>(&Cin[(size_t)s1 * 256 + l * 32]);
            const bf8 a0 = p0[0], a1 = p0[1], a2 = p0[2], a3 = p0[3];
            const bf8 c0 = p1[0], c1 = p1[1], c2 = p1[2], c3 = p1[3];
            #pragma unroll
            for (int i = 0; i < 8; ++i) {
                acc[i]      += b2f(a0[i]) + b2f(c0[i]);
                acc[8 + i]  += b2f(a1[i]) + b2f(c1[i]);
                acc[16 + i] += b2f(a2[i]) + b2f(c2[i]);
                acc[24 + i] += b2f(a3[i]) + b2f(c3[i]);
            }
        }
        if (e < end) {
            const int s0 = inlds ? lcsr[e - beg0] : csr[e];
            const bf8* p0 = reinterpret_cast<const bf8*>(&Cin[(size_t)s0 * 256 + l * 32]);
            const bf8 a0 = p0[0], a1 = p0[1], a2 = p0[2], a3 = p0[3];
            #pragma unroll
            for (int i = 0; i < 8; ++i) {
                acc[i] += b2f(a0[i]); acc[8 + i] += b2f(a1[i]);
                acc[16 + i] += b2f(a2[i]); acc[24 + i] += b2f(a3[i]);
            }
        }
        const float invd = 1.0f / fmaxf((float)(end - beg), 1.0f);
        const bf8* zp = reinterpret_cast<const bf8*>(&Cin[(size_t)node * 256 + 128 + l * 32]);
        const float* bp = bias + l * 32;
        #pragma unroll
        for (int c8 = 0; c8 < 4; ++c8) {
            const bf8 z = zp[c8];
            bf8 o;
            #pragma unroll
            for (int i = 0; i < 8; ++i) {
                float h = acc[c8 * 8 + i] * invd + b2f(z[i]) + bp[c8 * 8 + i];
                h = h > 0.f ? h : expf(h) - 1.f;  // ELU
                o[i] = (short)f2bf(h);
            }
            const unsigned byte = (unsigned)((g * 256 + l * 64 + c8 * 16) ^ ((g & 7) << 4));
            *reinterpret_cast<bf8*>(tbase + byte) = o;
        }
    } else {
        const bf8 zz = (bf8){0,0,0,0,0,0,0,0};
        #pragma unroll
        for (int c8 = 0; c8 < 4; ++c8) {
            const unsigned byte = (unsigned)((g * 256 + l * 64 + c8 * 16) ^ ((g & 7) << 4));
            *reinterpret_cast<bf8*>(tbase + byte) = zz;
        }
    }

    // ---- phase B: dual GEMM from LDS tile ----
    const int wave = tid >> 6;
    const int lane = tid & 63;
    bf8 bfr[CFW][4];
    const bf8* bpf = reinterpret_cast<const bf8*>(Bp);
    #pragma unroll
    for (int cf = 0; cf < CFW; ++cf)
        #pragma unroll
        for (int ks = 0; ks < 4; ++ks)
            bfr[cf][ks] = bpf[((wave * CFW + cf) * 4 + ks) * 64 + lane];
    __syncthreads();

    const int rlane = lane & 15, kc = lane >> 4;
    #pragma unroll
    for (int rf = 0; rf < 4; ++rf) {
        const int row = rf * 16 + rlane;
        bf8 afr[4];
        #pragma unroll
        for (int ks = 0; ks < 4; ++ks) {
            const unsigned byte = (unsigned)((row * 256 + ks * 64 + kc * 16) ^ ((row & 7) << 4));
            afr[ks] = *reinterpret_cast<const bf8*>(tbase + byte);
        }
        f4 acc[CFW];
        #pragma unroll
        for (int cf = 0; cf < CFW; ++cf) acc[cf] = (f4){0.f, 0.f, 0.f, 0.f};
        #pragma unroll
        for (int ks = 0; ks < 4; ++ks)
            #pragma unroll
            for (int cf = 0; cf < CFW; ++cf)
                acc[cf] = __builtin_amdgcn_mfma_f32_16x16x32_bf16(afr[ks], bfr[cf][ks], acc[cf], 0, 0, 0);
        const int orow0 = n0 + rf * 16 + (lane >> 4) * 4;
        #pragma unroll
        for (int j = 0; j < 4; ++j) {
            const int orow = orow0 + j;
            if (orow < NN) {
                #pragma unroll
                for (int cf = 0; cf < CFW; ++cf)
                    Cout[(size_t)orow * NCOLOUT + (wave * CFW + cf) * 16 + rlane] = f2bf(acc[cf][j]);
            }
        }
    }
}

// ---------------- launch 6: final gather + combine + log_softmax ----------------
// Cin rows are [Y(64) | Z(64)] bf16 (NCOL=128)
__global__ __launch_bounds__(256) void gathlsm_k(const int* __restrict__ rowptr,
                                                 const int* __restrict__ csr,
                                                 const unsigned short* __restrict__ Cin,
                                                 const float* __restrict__ bias,
                                                 float* __restrict__ lout) {
    const int g = threadIdx.x / 8;     // 32 nodes per block
    const int l = threadIdx.x % 8;     // 8 lanes per node, 8 cols each
    const int n = blockIdx.x * 32 + g;
    if (n >= NN) return;
    const int beg = rowptr[n], end = rowptr[n + 1];

    float acc[8] = {0.f, 0.f, 0.f, 0.f, 0.f, 0.f, 0.f, 0.f};
    int e = beg;
    for (; e + 1 < end; e += 2) {
        const int s0 = csr[e], s1 = csr[e + 1];
        const bf8 v0 = *reinterpret_cast<const bf8*>(&Cin[(size_t)s0 * 128 + l * 8]);
        const bf8 v1 = *reinterpret_cast<const bf8*>(&Cin[(size_t)s1 * 128 + l * 8]);
        #pragma unroll
        for (int i = 0; i < 8; ++i) acc[i] += b2f(v0[i]) + b2f(v1[i]);
    }
    if (e < end) {
        const int s0 = csr[e];
        const bf8 v0 = *reinterpret_cast<const bf8*>(&Cin[(size_t)s0 * 128 + l * 8]);
        #pragma unroll
        for (int i = 0; i < 8; ++i) acc[i] += b2f(v0[i]);
    }
    const float inv = 1.0f / fmaxf((float)(end - beg), 1.0f);
    const bf8 z = *reinterpret_cast<const bf8*>(&Cin[(size_t)n * 128 + 64 + l * 8]);
    float h[8];
    #pragma unroll
    for (int i = 0; i < 8; ++i) h[i] = acc[i] * inv + b2f(z[i]) + bias[l * 8 + i];

    float m = h[0];
    #pragma unroll
    for (int i = 1; i < 8; ++i) m = fmaxf(m, h[i]);
    #pragma unroll
    for (int o = 1; o < 8; o <<= 1) m = fmaxf(m, __shfl_xor(m, o, 64));
    float s = 0.f;
    #pragma unroll
    for (int i = 0; i < 8; ++i) s += expf(h[i] - m);
    #pragma unroll
    for (int o = 1; o < 8; o <<= 1) s += __shfl_xor(s, o, 64);
    const float lg = m + logf(s);
    float4 o0, o1;
    o0.x = h[0] - lg; o0.y = h[1] - lg; o0.z = h[2] - lg; o0.w = h[3] - lg;
    o1.x = h[4] - lg; o1.y = h[5] - lg; o1.z = h[6] - lg; o1.w = h[7] - lg;
    float* op = &lout[(size_t)n * 64 + l * 8];
    *reinterpret_cast<float4*>(op) = o0;
    *reinterpret_cast<float4*>(op + 4) = o1;
}

extern "C" void kernel_launch(void* const* d_in, const int* in_sizes, int n_in,
                              void* d_out, int out_size, void* d_ws, size_t ws_size,
                              hipStream_t stream) {
    const float* x   = (const float*)d_in[0];
    const int*   ei  = (const int*)d_in[1];
    const float* Wl0 = (const float*)d_in[2];
    const float* bl0 = (const float*)d_in[3];
    const float* Wr0 = (const float*)d_in[4];
    const float* Wl1 = (const float*)d_in[5];
    const float* bl1 = (const float*)d_in[6];
    const float* Wr1 = (const float*)d_in[7];
    const float* Wl2 = (const float*)d_in[8];
    const float* bl2 = (const float*)d_in[9];
    const float* Wr2 = (const float*)d_in[10];
    float* out = (float*)d_out;

    unsigned short* bufA = (unsigned short*)d_ws;              // [NPAD][256]
    unsigned short* bufB = bufA + (size_t)NPAD * 256;          // [NPAD][256]
    unsigned short* Bp   = bufB + (size_t)NPAD * 256;          // 81920
    int* rowptr = (int*)(Bp + 81920);                          // NN+2
    int* cursor = rowptr + (NN + 2);                           // NBK*CSTRIDE
    int* csr    = cursor + NBK * CSTRIDE;                      // NE
    unsigned int* bucket = (unsigned int*)(csr + NE);          // NBK*BCAP

    zero_k<<<1, NBK, 0, stream>>>(cursor, rowptr);
    prep_k<<<NFB + 320, 256, 0, stream>>>(ei, cursor, bucket, Wl0, Wr0, Wl1, Wr1, Wl2, Wr2, Bp);
    mid_k<<<NBK + GB, 256, 0, stream>>>(bucket, cursor, rowptr, csr, x, Bp, bufA);
    fused_k<256><<<GB, 256, 0, stream>>>(rowptr, csr, bufA, bl0, Bp + 32768, bufB);
    fused_k<128><<<GB, 256, 0, stream>>>(rowptr, csr, bufB, bl1, Bp + 65536, bufA);
    gathlsm_k<<<(NN + 31) / 32, 256, 0, stream>>>(rowptr, csr, bufA, bl2, out);
}

// Round 8
// 132.721 us; speedup vs baseline: 27.7077x; 1.1903x over previous
//
#include <hip/hip_runtime.h>
#include <hip/hip_bf16.h>

#define NN 50000
#define NE 800000
#define NPAD 50048   // rows padded to multiple of 64
#define NBK 512      // coarse buckets for CSR build
#define RNG 98       // nodes per bucket (512*98 = 50176 >= NN)
#define BCAP 2560    // bucket capacity (mean 1568, +25 sigma)
#define CSTRIDE 16   // cursor padding: 1 cursor per 64B line
#define EPB 4096     // edges per block in bucket fill
#define NFB ((NE + EPB - 1) / EPB)   // 196 blocks
#define CSRCAP 1536  // per-64-node-block CSR window (mean 1024)
#define GB (NPAD / 64)               // 782 row-blocks

typedef __attribute__((ext_vector_type(8))) short bf8;       // 8 bf16 = 4 VGPR
typedef __attribute__((ext_vector_type(4))) float f4;
typedef __attribute__((ext_vector_type(2))) float f2v;
typedef __attribute__((ext_vector_type(4))) unsigned int u4v; // 16B

__device__ __forceinline__ unsigned short f2bf(float f) {  // RNE
    union { float f; unsigned int u; } x; x.f = f;
    unsigned int r = x.u + 0x7fffu + ((x.u >> 16) & 1u);
    return (unsigned short)(r >> 16);
}
__device__ __forceinline__ float b2f(short s) {
    union { unsigned int u; float f; } x;
    x.u = ((unsigned int)(unsigned short)s) << 16;
    return x.f;
}
__device__ __forceinline__ unsigned char f2fp8(float v) {  // e4m3 (OCP), RNE
    return (unsigned char)(__builtin_amdgcn_cvt_pk_fp8_f32(v, v, 0, false) & 0xff);
}
// accumulate 16 fp8 (one 16B vector) into acc[0..15]
__device__ __forceinline__ void acc16_fp8(float* acc, u4v v) {
    #pragma unroll
    for (int t = 0; t < 4; ++t) {
        f2v lo = __builtin_amdgcn_cvt_pk_f32_fp8((int)v[t], false);
        f2v hi = __builtin_amdgcn_cvt_pk_f32_fp8((int)v[t], true);
        acc[t * 4 + 0] += lo.x; acc[t * 4 + 1] += lo.y;
        acc[t * 4 + 2] += hi.x; acc[t * 4 + 3] += hi.y;
    }
}

// ---------------- launch 1: zero bucket cursors ----------------
__global__ void zero_k(int* __restrict__ cursor, int* __restrict__ rowptr) {
    cursor[threadIdx.x * CSTRIDE] = 0;
    if (threadIdx.x == 0) rowptr[NN] = NE;
}

// ---------------- launch 2: bucket fill (blocks 0..NFB-1) || pack weights ----------------
__global__ __launch_bounds__(256) void prep_k(const int* __restrict__ ei,
                                              int* __restrict__ cursor,
                                              unsigned int* __restrict__ bucket,
                                              const float* __restrict__ Wl0, const float* __restrict__ Wr0,
                                              const float* __restrict__ Wl1, const float* __restrict__ Wr1,
                                              const float* __restrict__ Wl2, const float* __restrict__ Wr2,
                                              unsigned short* __restrict__ Bp) {
    __shared__ unsigned int sorted[EPB];
    __shared__ unsigned short sbuck[EPB];
    __shared__ int hist[NBK], ofs[NBK], gpos[NBK], stmp[256];
    const int tid = threadIdx.x;
    if (blockIdx.x >= NFB) {
        int idx = (blockIdx.x - NFB) * 256 + tid;
        const float *Wl, *Wr;
        int Mo, local;
        unsigned short* out;
        if (idx < 32768)       { Wl = Wl0; Wr = Wr0; Mo = 128; out = Bp;         local = idx; }
        else if (idx < 65536)  { Wl = Wl1; Wr = Wr1; Mo = 128; out = Bp + 32768; local = idx - 32768; }
        else if (idx < 81920)  { Wl = Wl2; Wr = Wr2; Mo = 64;  out = Bp + 65536; local = idx - 65536; }
        else return;
        int ncol = 2 * Mo;
        int k = local / ncol, c = local % ncol;
        float v = (c < Mo) ? Wl[k * Mo + c] : Wr[k * Mo + (c - Mo)];
        int cf = c >> 4, ks = k >> 5;
        int lane = (c & 15) | (((k & 31) >> 3) << 4);
        int i = k & 7;
        out[(((cf << 2) | ks) * 64 + lane) * 8 + i] = f2bf(v);
        return;
    }
    const int e0 = blockIdx.x * EPB;
    const int n = (NE - e0) < EPB ? (NE - e0) : EPB;

    for (int i = tid; i < NBK; i += 256) hist[i] = 0;
    __syncthreads();

    unsigned int ent[EPB / 256];
    short bks[EPB / 256];
    #pragma unroll
    for (int j = 0; j < EPB / 256; ++j) {
        const int li = tid + j * 256;
        int b = -1; unsigned v = 0;
        if (li < n) {
            const int e = e0 + li;
            const int s = ei[e];
            const int d = ei[NE + e];
            b = d / RNG;
            v = (unsigned)s | ((unsigned)(d - b * RNG) << 16);
            atomicAdd(&hist[b], 1);
        }
        ent[j] = v; bks[j] = (short)b;
    }
    __syncthreads();

    const int p0 = hist[2 * tid], p1 = hist[2 * tid + 1];
    stmp[tid] = p0 + p1;
    __syncthreads();
    #pragma unroll
    for (int off = 1; off < 256; off <<= 1) {
        const int t = (tid >= off) ? stmp[tid - off] : 0;
        __syncthreads();
        stmp[tid] += t;
        __syncthreads();
    }
    const int pbase = stmp[tid] - p0 - p1;
    ofs[2 * tid] = pbase;
    ofs[2 * tid + 1] = pbase + p0;
    __syncthreads();

    for (int i = tid; i < NBK; i += 256) {
        const int c = hist[i];
        gpos[i] = c ? atomicAdd(&cursor[i * CSTRIDE], c) : 0;
    }
    for (int i = tid; i < NBK; i += 256) hist[i] = ofs[i];
    __syncthreads();
    #pragma unroll
    for (int j = 0; j < EPB / 256; ++j) {
        if (bks[j] >= 0) {
            const int r = atomicAdd(&hist[(int)bks[j]], 1);
            sorted[r] = ent[j];
            sbuck[r] = (unsigned short)bks[j];
        }
    }
    __syncthreads();
    for (int i = tid; i < n; i += 256) {
        const int b = sbuck[i];
        const int idx = gpos[b] + (i - ofs[b]);
        if (idx < BCAP) bucket[(size_t)b * BCAP + idx] = sorted[i];
    }
}

// ---------------- launch 3: csr_build (blocks 0..511) || layer-1 GEMM from fp32 x ----------------
// GEMM epilogue: cols 0..127 -> Yq (fp8), cols 128..255 -> Z (bf16)
__global__ __launch_bounds__(256) void mid_k(const unsigned int* __restrict__ bucket,
                                             const int* __restrict__ cursor,
                                             int* __restrict__ rowptr, int* __restrict__ csr,
                                             const float* __restrict__ x,
                                             const unsigned short* __restrict__ Bp,
                                             unsigned char* __restrict__ Yq,
                                             unsigned short* __restrict__ Z) {
    __shared__ unsigned int ent[BCAP];
    __shared__ int hist[RNG], lcur[RNG], sofs[NBK], stmp[256];
    const int tid = threadIdx.x;
    if (blockIdx.x < NBK) {
        const int b = blockIdx.x;
        const int c0 = cursor[(2 * tid) * CSTRIDE];
        const int c1 = cursor[(2 * tid + 1) * CSTRIDE];
        stmp[tid] = c0 + c1;
        __syncthreads();
        #pragma unroll
        for (int off = 1; off < 256; off <<= 1) {
            const int t = (tid >= off) ? stmp[tid - off] : 0;
            __syncthreads();
            stmp[tid] += t;
            __syncthreads();
        }
        const int pbase = stmp[tid] - c0 - c1;
        sofs[2 * tid] = pbase;
        sofs[2 * tid + 1] = pbase + c0;
        for (int i = tid; i < RNG; i += 256) { hist[i] = 0; lcur[i] = 0; }
        __syncthreads();

        const int sz0 = cursor[b * CSTRIDE];
        const int sz = sz0 < BCAP ? sz0 : BCAP;
        const int gbase = sofs[b];
        for (int i = tid; i < sz; i += 256) {
            unsigned v = bucket[(size_t)b * BCAP + i];
            ent[i] = v;
            atomicAdd(&hist[v >> 16], 1);
        }
        __syncthreads();
        if (tid == 0) {
            int acc = 0;
            #pragma unroll 2
            for (int i = 0; i < RNG; ++i) { int c = hist[i]; hist[i] = acc; acc += c; }
        }
        __syncthreads();
        const int n0 = b * RNG;
        for (int i = tid; i < RNG; i += 256) {
            int nn = n0 + i;
            if (nn < NN) rowptr[nn] = gbase + hist[i];
        }
        for (int i = tid; i < sz; i += 256) {
            unsigned v = ent[i];
            int dloc = v >> 16;
            int r = atomicAdd(&lcur[dloc], 1);
            csr[gbase + hist[dloc] + r] = (int)(v & 0xffffu);
        }
        return;
    }
    // ---- layer-1 dual GEMM ----
    const int wave = tid >> 6;
    const int lane = tid & 63;
    const int r0 = (blockIdx.x - NBK) * 64;

    bf8 bfr[4][4];
    const bf8* bp = reinterpret_cast<const bf8*>(Bp);
    #pragma unroll
    for (int cf = 0; cf < 4; ++cf)
        #pragma unroll
        for (int ks = 0; ks < 4; ++ks)
            bfr[cf][ks] = bp[((wave * 4 + cf) * 4 + ks) * 64 + lane];

    const int rlane = lane & 15, kc = lane >> 4;
    #pragma unroll
    for (int rf = 0; rf < 4; ++rf) {
        const int arow = r0 + rf * 16 + rlane;
        const bool ok = arow < NN;
        const float4* ap = reinterpret_cast<const float4*>(x + (size_t)arow * 128);
        bf8 afr[4];
        #pragma unroll
        for (int ks = 0; ks < 4; ++ks) {
            float4 a0 = make_float4(0.f,0.f,0.f,0.f), a1 = a0;
            if (ok) { a0 = ap[ks * 8 + kc * 2]; a1 = ap[ks * 8 + kc * 2 + 1]; }
            bf8 t;
            t[0]=(short)f2bf(a0.x); t[1]=(short)f2bf(a0.y); t[2]=(short)f2bf(a0.z); t[3]=(short)f2bf(a0.w);
            t[4]=(short)f2bf(a1.x); t[5]=(short)f2bf(a1.y); t[6]=(short)f2bf(a1.z); t[7]=(short)f2bf(a1.w);
            afr[ks] = t;
        }
        f4 acc[4];
        #pragma unroll
        for (int cf = 0; cf < 4; ++cf) acc[cf] = (f4){0.f, 0.f, 0.f, 0.f};
        #pragma unroll
        for (int ks = 0; ks < 4; ++ks)
            #pragma unroll
            for (int cf = 0; cf < 4; ++cf)
                acc[cf] = __builtin_amdgcn_mfma_f32_16x16x32_bf16(afr[ks], bfr[cf][ks], acc[cf], 0, 0, 0);
        const int orow0 = r0 + rf * 16 + (lane >> 4) * 4;
        #pragma unroll
        for (int j = 0; j < 4; ++j) {
            const int orow = orow0 + j;
            if (orow < NN) {
                #pragma unroll
                for (int cf = 0; cf < 4; ++cf) {
                    const int col = (wave * 4 + cf) * 16 + rlane;
                    const float v = acc[cf][j];
                    if (col < 128) Yq[(size_t)orow * 128 + col] = f2fp8(v);
                    else           Z[(size_t)orow * 128 + (col - 128)] = f2bf(v);
                }
            }
        }
    }
}

// ---------------- launches 4,5: fused gather+combine+ELU+GEMM ----------------
// Inputs: Yq_in [NPAD][128] fp8, Z_in [NPAD][128] bf16.
// Phase A: h = ELU(mean(Yq[neigh]) + Z + bias) -> XOR-swizzled LDS tile [64][128] bf16
// Phase B: dual GEMM; cols<MOUT -> Yq_out fp8, cols>=MOUT -> Z_out bf16
template<int MOUT>
__global__ __launch_bounds__(256) void fused_k(const int* __restrict__ rowptr,
                                               const int* __restrict__ csr,
                                               const unsigned char* __restrict__ Yq_in,
                                               const unsigned short* __restrict__ Z_in,
                                               const float* __restrict__ bias,
                                               const unsigned short* __restrict__ Bp,
                                               unsigned char* __restrict__ Yq_out,
                                               unsigned short* __restrict__ Z_out) {
    constexpr int CFW = 2 * MOUT / 64;     // col-frags per wave (4 or 2)
    __shared__ int lcsr[CSRCAP];
    __shared__ unsigned short tile[64 * 128];  // XOR-swizzled: byte ^= (row&7)<<4
    const int tid = threadIdx.x;
    const int n0 = blockIdx.x * 64;
    const int nend = (n0 + 64 > NN) ? NN : (n0 + 64);
    const int beg0 = rowptr[n0];
    const int tot = rowptr[nend] - beg0;
    const bool inlds = tot <= CSRCAP;
    if (inlds) for (int i = tid; i < tot; i += 256) lcsr[i] = csr[beg0 + i];
    __syncthreads();

    // ---- phase A: gather (4 lanes/node, 32 fp8 cols each; 4-edge unroll = 8x16B in flight) ----
    const int g = tid >> 2, l = tid & 3;
    const int node = n0 + g;
    char* tbase = reinterpret_cast<char*>(tile);
    if (node < NN) {
        const int beg = rowptr[node], end = rowptr[node + 1];
        float acc[32];
        #pragma unroll
        for (int i = 0; i < 32; ++i) acc[i] = 0.f;
        int e = beg;
        for (; e + 4 <= end; e += 4) {
            int ss[4];
            #pragma unroll
            for (int j = 0; j < 4; ++j) ss[j] = inlds ? lcsr[e + j - beg0] : csr[e + j];
            u4v u[8];
            #pragma unroll
            for (int j = 0; j < 4; ++j) {
                const u4v* p = reinterpret_cast<const u4v*>(Yq_in + (size_t)ss[j] * 128 + l * 32);
                u[2 * j] = p[0]; u[2 * j + 1] = p[1];
            }
            #pragma unroll
            for (int j = 0; j < 4; ++j) { acc16_fp8(acc, u[2 * j]); acc16_fp8(acc + 16, u[2 * j + 1]); }
        }
        for (; e < end; ++e) {
            const int s0 = inlds ? lcsr[e - beg0] : csr[e];
            const u4v* p = reinterpret_cast<const u4v*>(Yq_in + (size_t)s0 * 128 + l * 32);
            const u4v a = p[0], b = p[1];
            acc16_fp8(acc, a); acc16_fp8(acc + 16, b);
        }
        const float invd = 1.0f / fmaxf((float)(end - beg), 1.0f);
        const bf8* zp = reinterpret_cast<const bf8*>(&Z_in[(size_t)node * 128 + l * 32]);
        const float* bp = bias + l * 32;
        #pragma unroll
        for (int c8 = 0; c8 < 4; ++c8) {
            const bf8 z = zp[c8];
            bf8 o;
            #pragma unroll
            for (int i = 0; i < 8; ++i) {
                float h = acc[c8 * 8 + i] * invd + b2f(z[i]) + bp[c8 * 8 + i];
                h = h > 0.f ? h : expf(h) - 1.f;  // ELU
                o[i] = (short)f2bf(h);
            }
            const unsigned byte = (unsigned)((g * 256 + l * 64 + c8 * 16) ^ ((g & 7) << 4));
            *reinterpret_cast<bf8*>(tbase + byte) = o;
        }
    } else {
        const bf8 zz = (bf8){0,0,0,0,0,0,0,0};
        #pragma unroll
        for (int c8 = 0; c8 < 4; ++c8) {
            const unsigned byte = (unsigned)((g * 256 + l * 64 + c8 * 16) ^ ((g & 7) << 4));
            *reinterpret_cast<bf8*>(tbase + byte) = zz;
        }
    }

    // ---- phase B: dual GEMM from LDS tile ----
    const int wave = tid >> 6;
    const int lane = tid & 63;
    bf8 bfr[CFW][4];
    const bf8* bpf = reinterpret_cast<const bf8*>(Bp);
    #pragma unroll
    for (int cf = 0; cf < CFW; ++cf)
        #pragma unroll
        for (int ks = 0; ks < 4; ++ks)
            bfr[cf][ks] = bpf[((wave * CFW + cf) * 4 + ks) * 64 + lane];
    __syncthreads();

    const int rlane = lane & 15, kc = lane >> 4;
    #pragma unroll
    for (int rf = 0; rf < 4; ++rf) {
        const int row = rf * 16 + rlane;
        bf8 afr[4];
        #pragma unroll
        for (int ks = 0; ks < 4; ++ks) {
            const unsigned byte = (unsigned)((row * 256 + ks * 64 + kc * 16) ^ ((row & 7) << 4));
            afr[ks] = *reinterpret_cast<const bf8*>(tbase + byte);
        }
        f4 acc[CFW];
        #pragma unroll
        for (int cf = 0; cf < CFW; ++cf) acc[cf] = (f4){0.f, 0.f, 0.f, 0.f};
        #pragma unroll
        for (int ks = 0; ks < 4; ++ks)
            #pragma unroll
            for (int cf = 0; cf < CFW; ++cf)
                acc[cf] = __builtin_amdgcn_mfma_f32_16x16x32_bf16(afr[ks], bfr[cf][ks], acc[cf], 0, 0, 0);
        const int orow0 = n0 + rf * 16 + (lane >> 4) * 4;
        #pragma unroll
        for (int j = 0; j < 4; ++j) {
            const int orow = orow0 + j;
            if (orow < NN) {
                #pragma unroll
                for (int cf = 0; cf < CFW; ++cf) {
                    const int col = (wave * CFW + cf) * 16 + rlane;
                    const float v = acc[cf][j];
                    if (col < MOUT) Yq_out[(size_t)orow * MOUT + col] = f2fp8(v);
                    else            Z_out[(size_t)orow * MOUT + (col - MOUT)] = f2bf(v);
                }
            }
        }
    }
}

// ---------------- launch 6: final gather + combine + log_softmax ----------------
// Yq2 [NPAD][64] fp8 (64B rows = 1 line), Z2 [NPAD][64] bf16
__global__ __launch_bounds__(256) void gathlsm_k(const int* __restrict__ rowptr,
                                                 const int* __restrict__ csr,
                                                 const unsigned char* __restrict__ Yq2,
                                                 const unsigned short* __restrict__ Z2,
                                                 const float* __restrict__ bias,
                                                 float* __restrict__ lout) {
    __shared__ int lcsr[CSRCAP];
    const int tid = threadIdx.x;
    const int n0 = blockIdx.x * 64;
    const int nend = (n0 + 64 > NN) ? NN : (n0 + 64);
    const int beg0 = rowptr[n0];
    const int tot = rowptr[nend] - beg0;
    const bool inlds = tot <= CSRCAP;
    if (inlds) for (int i = tid; i < tot; i += 256) lcsr[i] = csr[beg0 + i];
    __syncthreads();

    const int g = tid >> 2, l = tid & 3;   // 64 nodes/block, 16 cols/lane
    const int n = n0 + g;
    if (n >= NN) return;
    const int beg = rowptr[n], end = rowptr[n + 1];

    float acc[16];
    #pragma unroll
    for (int i = 0; i < 16; ++i) acc[i] = 0.f;
    int e = beg;
    for (; e + 8 <= end; e += 8) {   // 8-edge unroll: 8 lines in flight/lane
        int ss[8];
        #pragma unroll
        for (int j = 0; j < 8; ++j) ss[j] = inlds ? lcsr[e + j - beg0] : csr[e + j];
        u4v u[8];
        #pragma unroll
        for (int j = 0; j < 8; ++j)
            u[j] = *reinterpret_cast<const u4v*>(Yq2 + (size_t)ss[j] * 64 + l * 16);
        #pragma unroll
        for (int j = 0; j < 8; ++j) acc16_fp8(acc, u[j]);
    }
    for (; e < end; ++e) {
        const int s0 = inlds ? lcsr[e - beg0] : csr[e];
        acc16_fp8(acc, *reinterpret_cast<const u4v*>(Yq2 + (size_t)s0 * 64 + l * 16));
    }
    const float inv = 1.0f / fmaxf((float)(end - beg), 1.0f);
    const bf8* zp = reinterpret_cast<const bf8*>(&Z2[(size_t)n * 64 + l * 16]);
    const bf8 z0 = zp[0], z1 = zp[1];
    float h[16];
    #pragma unroll
    for (int i = 0; i < 8; ++i) {
        h[i]     = acc[i]     * inv + b2f(z0[i]) + bias[l * 16 + i];
        h[8 + i] = acc[8 + i] * inv + b2f(z1[i]) + bias[l * 16 + 8 + i];
    }
    float m = h[0];
    #pragma unroll
    for (int i = 1; i < 16; ++i) m = fmaxf(m, h[i]);
    m = fmaxf(m, __shfl_xor(m, 1, 64));
    m = fmaxf(m, __shfl_xor(m, 2, 64));
    float s = 0.f;
    #pragma unroll
    for (int i = 0; i < 16; ++i) s += expf(h[i] - m);
    s += __shfl_xor(s, 1, 64);
    s += __shfl_xor(s, 2, 64);
    const float lg = m + logf(s);
    float* op = &lout[(size_t)n * 64 + l * 16];
    #pragma unroll
    for (int q = 0; q < 4; ++q) {
        float4 o;
        o.x = h[q * 4 + 0] - lg; o.y = h[q * 4 + 1] - lg;
        o.z = h[q * 4 + 2] - lg; o.w = h[q * 4 + 3] - lg;
        *reinterpret_cast<float4*>(op + q * 4) = o;
    }
}

extern "C" void kernel_launch(void* const* d_in, const int* in_sizes, int n_in,
                              void* d_out, int out_size, void* d_ws, size_t ws_size,
                              hipStream_t stream) {
    const float* x   = (const float*)d_in[0];
    const int*   ei  = (const int*)d_in[1];
    const float* Wl0 = (const float*)d_in[2];
    const float* bl0 = (const float*)d_in[3];
    const float* Wr0 = (const float*)d_in[4];
    const float* Wl1 = (const float*)d_in[5];
    const float* bl1 = (const float*)d_in[6];
    const float* Wr1 = (const float*)d_in[7];
    const float* Wl2 = (const float*)d_in[8];
    const float* bl2 = (const float*)d_in[9];
    const float* Wr2 = (const float*)d_in[10];
    float* out = (float*)d_out;

    unsigned char*  Yqa = (unsigned char*)d_ws;                        // [NPAD][128] fp8
    unsigned char*  Yqb = Yqa + (size_t)NPAD * 128;                    // [NPAD][128] fp8
    unsigned short* Za  = (unsigned short*)(Yqb + (size_t)NPAD * 128); // [NPAD][128] bf16
    unsigned short* Zb  = Za + (size_t)NPAD * 128;                     // [NPAD][128] bf16
    unsigned short* Bp  = Zb + (size_t)NPAD * 128;                     // 81920
    int* rowptr = (int*)(Bp + 81920);                                  // NN+2
    int* cursor = rowptr + (NN + 2);                                   // NBK*CSTRIDE
    int* csr    = cursor + NBK * CSTRIDE;                              // NE
    unsigned int* bucket = (unsigned int*)(csr + NE);                  // NBK*BCAP

    zero_k<<<1, NBK, 0, stream>>>(cursor, rowptr);
    prep_k<<<NFB + 320, 256, 0, stream>>>(ei, cursor, bucket, Wl0, Wr0, Wl1, Wr1, Wl2, Wr2, Bp);
    mid_k<<<NBK + GB, 256, 0, stream>>>(bucket, cursor, rowptr, csr, x, Bp, Yqa, Za);
    fused_k<128><<<GB, 256, 0, stream>>>(rowptr, csr, Yqa, Za, bl0, Bp + 32768, Yqb, Zb);
    fused_k<64><<<GB, 256, 0, stream>>>(rowptr, csr, Yqb, Zb, bl1, Bp + 65536, Yqa, Za);
    gathlsm_k<<<GB, 256, 0, stream>>>(rowptr, csr, Yqa, Za, bl2, out);
}